// Round 4
// baseline (202.110 us; speedup 1.0000x reference)
//
#include <hip/hip_runtime.h>
#include <hip/hip_bf16.h>
#include <stdint.h>

#define DIM 512

typedef __bf16 bf16x8 __attribute__((ext_vector_type(8)));
typedef float f32x4 __attribute__((ext_vector_type(4)));

// ---- monotonic float<->uint encoding for atomicMax on signed floats ----
__device__ __forceinline__ unsigned fenc(float f) {
  unsigned u = __float_as_uint(f);
  return (u & 0x80000000u) ? ~u : (u | 0x80000000u);
}
__device__ __forceinline__ float fdec(unsigned e) {
  unsigned u = (e & 0x80000000u) ? (e & 0x7FFFFFFFu) : ~e;
  return __uint_as_float(u);
}

// ---- fast tanh: 1 - 2/(exp(2x)+1). ~5 VALU ops, exact at saturated tails.
__device__ __forceinline__ float tanh_fast(float x) {
  float e = __expf(2.0f * x);
  return 1.0f - 2.0f * __builtin_amdgcn_rcpf(e + 1.0f);
}

// ---- transpose last-2-dims + f32->bf16; z<16: A->At, z>=16: B->Bt ----
__global__ __launch_bounds__(256) void k_transpose_ab(const float* __restrict__ A,
                                                      const float* __restrict__ B,
                                                      __hip_bfloat16* __restrict__ At,
                                                      __hip_bfloat16* __restrict__ Bt) {
  __shared__ float tile[32][33];
  int x0 = blockIdx.x * 32, y0 = blockIdx.y * 32, z = blockIdx.z;
  const float* src = (z < 16 ? A + (size_t)z * DIM * DIM : B + (size_t)(z - 16) * DIM * DIM);
  __hip_bfloat16* dst = (z < 16 ? At + (size_t)z * DIM * DIM : Bt + (size_t)(z - 16) * DIM * DIM);
  int tx = threadIdx.x, ty = threadIdx.y;
#pragma unroll
  for (int k = 0; k < 4; ++k)
    tile[ty + 8 * k][tx] = src[(size_t)(y0 + ty + 8 * k) * DIM + x0 + tx];
  __syncthreads();
#pragma unroll
  for (int k = 0; k < 4; ++k)
    dst[(size_t)(x0 + ty + 8 * k) * DIM + y0 + tx] = __float2bfloat16(tile[tx][ty + 8 * k]);
}

__global__ __launch_bounds__(256) void k_transpose_u(const float* __restrict__ in,
                                                     __hip_bfloat16* __restrict__ out) {
  __shared__ float tile[32][33];
  int x0 = blockIdx.x * 32, y0 = blockIdx.y * 32;
  int tx = threadIdx.x, ty = threadIdx.y;
#pragma unroll
  for (int k = 0; k < 4; ++k)
    tile[ty + 8 * k][tx] = in[(size_t)(y0 + ty + 8 * k) * DIM + x0 + tx];
  __syncthreads();
#pragma unroll
  for (int k = 0; k < 4; ++k)
    out[(size_t)(x0 + ty + 8 * k) * DIM + y0 + tx] = __float2bfloat16(tile[tx][ty + 8 * k]);
}

// ---- init max buffers to enc(-inf) ----
__global__ void k_init_max(unsigned* p) { p[blockIdx.x * 256 + threadIdx.x] = 0x007FFFFFu; }

// ---- async global->LDS, 16B per lane ----
__device__ __forceinline__ void gload_lds16(const __hip_bfloat16* g, __hip_bfloat16* l) {
  __builtin_amdgcn_global_load_lds(
      (const __attribute__((address_space(1))) uint32_t*)g,
      (__attribute__((address_space(3))) uint32_t*)l, 16, 0, 0);
}

// ---- proj GEMM, M flattened to 8192: Pj[8192][512] = At[8192][512] @ Ut[512][512]^T
__global__ __launch_bounds__(256, 4) void k_proj64(const __hip_bfloat16* __restrict__ At,
                                                   const __hip_bfloat16* __restrict__ Ut,
                                                   __hip_bfloat16* __restrict__ Pj) {
  __shared__ __align__(16) __hip_bfloat16 lA[64 * 64];
  __shared__ __align__(16) __hip_bfloat16 lB[64 * 64];
  const int tid = threadIdx.x, lane = tid & 63, wid = tid >> 6;
  const int wm = wid >> 1, wn = wid & 1;
  const int rowA = blockIdx.x * 64, rowB = blockIdx.y * 64;

  int sl16[2], srow[2], scol[2];
#pragma unroll
  for (int i = 0; i < 2; ++i) {
    int d16 = i * 256 + tid;
    int r = d16 >> 3, p = d16 & 7;
    sl16[i] = d16;
    srow[i] = r;
    scol[i] = (p ^ (r & 7)) * 8;
  }

  f32x4 acc[2][2];
#pragma unroll
  for (int mi = 0; mi < 2; ++mi)
#pragma unroll
    for (int ni = 0; ni < 2; ++ni) acc[mi][ni] = (f32x4){0.f, 0.f, 0.f, 0.f};

  for (int k0 = 0; k0 < DIM; k0 += 64) {
#pragma unroll
    for (int i = 0; i < 2; ++i) {
      gload_lds16(At + (size_t)(rowA + srow[i]) * DIM + k0 + scol[i], &lA[sl16[i] * 8]);
      gload_lds16(Ut + (size_t)(rowB + srow[i]) * DIM + k0 + scol[i], &lB[sl16[i] * 8]);
    }
    __syncthreads();
#pragma unroll
    for (int ks = 0; ks < 2; ++ks) {
      bf16x8 af[2], bfr[2];
#pragma unroll
      for (int mi = 0; mi < 2; ++mi) {
        int r = wm * 32 + mi * 16 + (lane & 15);
        int p = (ks * 4 + (lane >> 4)) ^ (r & 7);
        af[mi] = *(const bf16x8*)&lA[r * 64 + p * 8];
      }
#pragma unroll
      for (int ni = 0; ni < 2; ++ni) {
        int r = wn * 32 + ni * 16 + (lane & 15);
        int p = (ks * 4 + (lane >> 4)) ^ (r & 7);
        bfr[ni] = *(const bf16x8*)&lB[r * 64 + p * 8];
      }
#pragma unroll
      for (int mi = 0; mi < 2; ++mi)
#pragma unroll
        for (int ni = 0; ni < 2; ++ni)
          acc[mi][ni] = __builtin_amdgcn_mfma_f32_16x16x32_bf16(af[mi], bfr[ni], acc[mi][ni], 0, 0, 0);
    }
    __syncthreads();
  }

#pragma unroll
  for (int mi = 0; mi < 2; ++mi) {
    int r0 = rowA + wm * 32 + mi * 16 + ((lane >> 4) << 2);
#pragma unroll
    for (int ni = 0; ni < 2; ++ni) {
      int c = rowB + wn * 32 + ni * 16 + (lane & 15);
#pragma unroll
      for (int j = 0; j < 4; ++j)
        Pj[(size_t)(r0 + j) * DIM + c] = __float2bfloat16(acc[mi][ni][j]);
    }
  }
}

// ---- deep-pipelined align GEMM + fused tanh/mask/max epilogue.
// Tile 256x128, 8 waves (512 thr), BK=64, TRIPLE-buffered LDS (144 KiB),
// 2 phases per K-tile, counted vmcnt(6) per tile (never 0 in main loop).
// Pipeline: compute(t) reads buf[t%3]; stage tile t+2 into buf[(t+2)%3]
// (freed at end of compute(t-1)); tile t+1's 6 loads drained by the
// vmcnt(6)+barrier at end of compute(t).
__global__ __launch_bounds__(512, 2) void k_align8(const __hip_bfloat16* __restrict__ Pj,
                                                   const __hip_bfloat16* __restrict__ Bt,
                                                   const float* __restrict__ msk,
                                                   unsigned* __restrict__ maxS,
                                                   unsigned* __restrict__ maxT) {
  __shared__ __align__(16) __hip_bfloat16 lA[3 * 256 * 64];  // 96 KiB
  __shared__ __align__(16) __hip_bfloat16 lB[3 * 128 * 64];  // 48 KiB
  const int tid = threadIdx.x;
  const int lane = tid & 63;
  const int wid = tid >> 6;
  const int wm = wid >> 1, wn = wid & 1;  // 4 x 2 waves -> per-wave 64x64 C
  const int hi = lane >> 4;

  // XCD-chunked decode: 2048 blocks, XCD k owns works [k*256,(k+1)*256) -> a in {2k,2k+1}
  const int bid = blockIdx.x;
  const int work = (bid & 7) * 256 + (bid >> 3);
  const int pair = work >> 3;            // a*16+b
  const int t8 = work & 7;
  const int a = pair >> 4, b = pair & 15;
  const int bm = t8 >> 2, bn = t8 & 3;   // 2 x 4 tiles of 256x128
  const int rowA0 = bm * 256, colB0 = bn * 128;

  const __hip_bfloat16* X = Pj + (size_t)a * DIM * DIM;
  const __hip_bfloat16* Y = Bt + (size_t)b * DIM * DIM;

  f32x4 acc[4][4];
#pragma unroll
  for (int mi = 0; mi < 4; ++mi)
#pragma unroll
    for (int ni = 0; ni < 4; ++ni) acc[mi][ni] = (f32x4){0.f, 0.f, 0.f, 0.f};

  // fragment row indices (per-thread constants)
  int rA[4], rB[4];
#pragma unroll
  for (int mi = 0; mi < 4; ++mi) rA[mi] = wm * 64 + mi * 16 + (lane & 15);
#pragma unroll
  for (int ni = 0; ni < 4; ++ni) rB[ni] = wn * 64 + ni * 16 + (lane & 15);

#define STAGE_A(kt)                                                                   \
  {                                                                                   \
    __hip_bfloat16* db = &lA[((kt) % 3) * 16384];                                     \
    _Pragma("unroll") for (int i = 0; i < 4; ++i) {                                   \
      int d16 = i * 512 + tid, r = d16 >> 3, p = d16 & 7;                             \
      gload_lds16(X + (size_t)(rowA0 + r) * DIM + (kt)*64 + ((p ^ (r & 7)) * 8),      \
                  db + d16 * 8);                                                      \
    }                                                                                 \
  }
#define STAGE_B(kt)                                                                   \
  {                                                                                   \
    __hip_bfloat16* db = &lB[((kt) % 3) * 8192];                                      \
    _Pragma("unroll") for (int i = 0; i < 2; ++i) {                                   \
      int d16 = i * 512 + tid, r = d16 >> 3, p = d16 & 7;                             \
      gload_lds16(Y + (size_t)(colB0 + r) * DIM + (kt)*64 + ((p ^ (r & 7)) * 8),      \
                  db + d16 * 8);                                                      \
    }                                                                                 \
  }

  // prologue: tiles 0 and 1 in flight; wait tile 0 (6 newest = tile 1 remain)
  STAGE_A(0); STAGE_B(0);
  STAGE_A(1); STAGE_B(1);
  asm volatile("s_waitcnt vmcnt(6)" ::: "memory");
  __builtin_amdgcn_s_barrier();

  for (int t = 0; t < 8; ++t) {
    const int boA = (t % 3) * 16384, boB = (t % 3) * 8192;
    // ---- phase 0 (ks=0): read frags, stage A(t+2), barrier, MFMA ----
    bf16x8 af[4], bv[4];
#pragma unroll
    for (int mi = 0; mi < 4; ++mi)
      af[mi] = *(const bf16x8*)&lA[boA + rA[mi] * 64 + ((hi ^ (rA[mi] & 7)) * 8)];
#pragma unroll
    for (int ni = 0; ni < 4; ++ni)
      bv[ni] = *(const bf16x8*)&lB[boB + rB[ni] * 64 + ((hi ^ (rB[ni] & 7)) * 8)];
    if (t + 2 < 8) STAGE_A(t + 2);
    __builtin_amdgcn_s_barrier();
    asm volatile("s_waitcnt lgkmcnt(0)" ::: "memory");
    __builtin_amdgcn_sched_barrier(0);
    __builtin_amdgcn_s_setprio(1);
#pragma unroll
    for (int mi = 0; mi < 4; ++mi)
#pragma unroll
      for (int ni = 0; ni < 4; ++ni)
        acc[mi][ni] = __builtin_amdgcn_mfma_f32_16x16x32_bf16(af[mi], bv[ni], acc[mi][ni], 0, 0, 0);
    __builtin_amdgcn_s_setprio(0);
    __builtin_amdgcn_s_barrier();
    // ---- phase 1 (ks=1): read frags, stage B(t+2), barrier, MFMA, vmcnt ----
#pragma unroll
    for (int mi = 0; mi < 4; ++mi)
      af[mi] = *(const bf16x8*)&lA[boA + rA[mi] * 64 + (((4 + hi) ^ (rA[mi] & 7)) * 8)];
#pragma unroll
    for (int ni = 0; ni < 4; ++ni)
      bv[ni] = *(const bf16x8*)&lB[boB + rB[ni] * 64 + (((4 + hi) ^ (rB[ni] & 7)) * 8)];
    if (t + 2 < 8) STAGE_B(t + 2);
    __builtin_amdgcn_s_barrier();
    asm volatile("s_waitcnt lgkmcnt(0)" ::: "memory");
    __builtin_amdgcn_sched_barrier(0);
    __builtin_amdgcn_s_setprio(1);
#pragma unroll
    for (int mi = 0; mi < 4; ++mi)
#pragma unroll
      for (int ni = 0; ni < 4; ++ni)
        acc[mi][ni] = __builtin_amdgcn_mfma_f32_16x16x32_bf16(af[mi], bv[ni], acc[mi][ni], 0, 0, 0);
    __builtin_amdgcn_s_setprio(0);
    if (t < 6)
      asm volatile("s_waitcnt vmcnt(6)" ::: "memory");  // drain tile t+1, keep t+2 in flight
    else
      asm volatile("s_waitcnt vmcnt(0)" ::: "memory");  // epilogue drain
    __builtin_amdgcn_s_barrier();
  }
#undef STAGE_A
#undef STAGE_B

  // ---- epilogue: tanh + mask + row/col max -> atomics ----
  const float* mk = msk + (size_t)a * DIM * DIM;
  float rmx[4][4], cmx[4];
#pragma unroll
  for (int mi = 0; mi < 4; ++mi)
#pragma unroll
    for (int j = 0; j < 4; ++j) rmx[mi][j] = -INFINITY;
#pragma unroll
  for (int ni = 0; ni < 4; ++ni) cmx[ni] = -INFINITY;

#pragma unroll
  for (int mi = 0; mi < 4; ++mi) {
    int s0 = rowA0 + wm * 64 + mi * 16 + hi * 4;
#pragma unroll
    for (int ni = 0; ni < 4; ++ni) {
      int tc = colB0 + wn * 64 + ni * 16 + (lane & 15);
#pragma unroll
      for (int j = 0; j < 4; ++j) {
        float v = tanh_fast(acc[mi][ni][j]) + mk[(size_t)(s0 + j) * DIM + tc];
        rmx[mi][j] = fmaxf(rmx[mi][j], v);
        cmx[ni] = fmaxf(cmx[ni], v);
      }
    }
  }

  // row-max over t: 16 lanes share a row
#pragma unroll
  for (int mi = 0; mi < 4; ++mi)
#pragma unroll
    for (int j = 0; j < 4; ++j) {
      float r = rmx[mi][j];
      r = fmaxf(r, __shfl_xor(r, 1));
      r = fmaxf(r, __shfl_xor(r, 2));
      r = fmaxf(r, __shfl_xor(r, 4));
      r = fmaxf(r, __shfl_xor(r, 8));
      if ((lane & 15) == 0) {
        int s = rowA0 + wm * 64 + mi * 16 + hi * 4 + j;
        atomicMax(&maxS[(size_t)pair * DIM + s], fenc(r));
      }
    }
  // col-max over s: 4 hi-groups share a col
#pragma unroll
  for (int ni = 0; ni < 4; ++ni) {
    float c = cmx[ni];
    c = fmaxf(c, __shfl_xor(c, 16));
    c = fmaxf(c, __shfl_xor(c, 32));
    if (lane < 16) {
      int tc = colB0 + wn * 64 + ni * 16 + lane;
      atomicMax(&maxT[(size_t)pair * DIM + tc], fenc(c));
    }
  }
}

// ---- softmax over the 512 max-logits of each (pair, side) ----
__global__ __launch_bounds__(64) void k_softmax(const unsigned* __restrict__ menc,
                                                float* __restrict__ sc) {
  int pair = blockIdx.x, side = blockIdx.y;
  const unsigned* buf = menc + (size_t)side * 256 * DIM + (size_t)pair * DIM;
  float* out = sc + (size_t)side * 256 * DIM + (size_t)pair * DIM;
  int lane = threadIdx.x;
  float v[8];
  float m = -INFINITY;
#pragma unroll
  for (int k = 0; k < 8; ++k) {
    v[k] = fdec(buf[lane + 64 * k]);
    m = fmaxf(m, v[k]);
  }
#pragma unroll
  for (int off = 1; off < 64; off <<= 1) m = fmaxf(m, __shfl_xor(m, off));
  float s = 0.f;
#pragma unroll
  for (int k = 0; k < 8; ++k) {
    v[k] = expf(v[k] - m);
    s += v[k];
  }
#pragma unroll
  for (int off = 1; off < 64; off <<= 1) s += __shfl_xor(s, off);
  float inv = 1.0f / s;
#pragma unroll
  for (int k = 0; k < 8; ++k) out[lane + 64 * k] = v[k] * inv;
}

// ---- attention-weighted pooling: out[pair][d] = sum_s mat[d][s] * score[pair][s]
__global__ __launch_bounds__(256) void k_pool(const float* __restrict__ A,
                                              const float* __restrict__ B,
                                              const float* __restrict__ sc,
                                              float* __restrict__ out) {
  __shared__ float ta[128][65];
  __shared__ float ts[16][128];
  int t = threadIdx.x;
  int d0 = blockIdx.x * 64;
  int y = blockIdx.y, side = blockIdx.z;
  const float* mat = (side ? B : A) + (size_t)y * DIM * DIM;
  const float* scb = sc + (size_t)side * 256 * DIM;
  float* ob = out + (size_t)side * 256 * DIM;
  int dl = t & 63, g = t >> 6;
  float acc[4] = {0.f, 0.f, 0.f, 0.f};
  for (int st = 0; st < 4; ++st) {
    __syncthreads();
#pragma unroll
    for (int i = 0; i < 32; ++i) {
      int idx = t + 256 * i;
      int r = idx >> 7, c = idx & 127;
      ta[c][r] = mat[(size_t)(d0 + r) * DIM + st * 128 + c];
    }
#pragma unroll
    for (int i = 0; i < 8; ++i) {
      int idx = t + 256 * i;
      int p = idx >> 7, s = idx & 127;
      int pair = side ? (p * 16 + y) : (y * 16 + p);
      ts[p][s] = scb[(size_t)pair * DIM + st * 128 + s];
    }
    __syncthreads();
    for (int s = 0; s < 128; ++s) {
      float v = ta[s][dl];
#pragma unroll
      for (int i = 0; i < 4; ++i) acc[i] += v * ts[g * 4 + i][s];
    }
  }
#pragma unroll
  for (int i = 0; i < 4; ++i) {
    int p = g * 4 + i;
    int pair = side ? (p * 16 + y) : (y * 16 + p);
    ob[(size_t)pair * DIM + d0 + dl] = acc[i];
  }
}

extern "C" void kernel_launch(void* const* d_in, const int* in_sizes, int n_in,
                              void* d_out, int out_size, void* d_ws, size_t ws_size,
                              hipStream_t stream) {
  (void)in_sizes; (void)n_in; (void)out_size; (void)ws_size;
  const float* A = (const float*)d_in[0];    // (16, 512, 512) d-major
  const float* B = (const float*)d_in[1];    // (16, 512, 512) d-major
  const float* msk = (const float*)d_in[2];  // (16, 512, 512)
  const float* U = (const float*)d_in[3];    // (512, 512)

  char* w = (char*)d_ws;
  __hip_bfloat16* At = (__hip_bfloat16*)(w + 0);         //  8 MB: [a][s][d] == [8192][512]
  __hip_bfloat16* Bt = (__hip_bfloat16*)(w + 8388608);   //  8 MB: [b][t][e]
  __hip_bfloat16* Ut = (__hip_bfloat16*)(w + 16777216);  //  512 KB: [e][d]
  __hip_bfloat16* Pj = (__hip_bfloat16*)(w + 17301504);  //  8 MB: [a][s][e] == [8192][512]
  unsigned* menc = (unsigned*)(w + 25690112);            //  1 MB: maxS | maxT
  float* sc = (float*)(w + 26738688);                    //  1 MB: scores
  unsigned* maxS = menc;
  unsigned* maxT = menc + 256 * DIM;

  k_transpose_ab<<<dim3(16, 16, 32), dim3(32, 8), 0, stream>>>(A, B, At, Bt);
  k_transpose_u<<<dim3(16, 16), dim3(32, 8), 0, stream>>>(U, Ut);
  k_init_max<<<1024, 256, 0, stream>>>(menc);
  k_proj64<<<dim3(128, 8), 256, 0, stream>>>(At, Ut, Pj);
  k_align8<<<2048, 512, 0, stream>>>(Pj, Bt, msk, maxS, maxT);
  k_softmax<<<dim3(256, 2), 64, 0, stream>>>(menc, sc);
  k_pool<<<dim3(8, 16, 2), 256, 0, stream>>>(A, B, sc, (float*)d_out);
}

// Round 5
// 200.479 us; speedup vs baseline: 1.0081x; 1.0081x over previous
//
#include <hip/hip_runtime.h>
#include <hip/hip_bf16.h>
#include <stdint.h>

#define DIM 512

typedef __bf16 bf16x8 __attribute__((ext_vector_type(8)));
typedef float f32x4 __attribute__((ext_vector_type(4)));

// ---- monotonic float<->uint encoding for atomicMax on signed floats ----
__device__ __forceinline__ unsigned fenc(float f) {
  unsigned u = __float_as_uint(f);
  return (u & 0x80000000u) ? ~u : (u | 0x80000000u);
}
__device__ __forceinline__ float fdec(unsigned e) {
  unsigned u = (e & 0x80000000u) ? (e & 0x7FFFFFFFu) : ~e;
  return __uint_as_float(u);
}

// ---- fast tanh: 1 - 2/(exp(2x)+1). ~5 VALU ops, exact at saturated tails.
__device__ __forceinline__ float tanh_fast(float x) {
  float e = __expf(2.0f * x);
  return 1.0f - 2.0f * __builtin_amdgcn_rcpf(e + 1.0f);
}

// ---- transpose last-2-dims + f32->bf16; z<16: A->At, z>=16: B->Bt ----
__global__ __launch_bounds__(256) void k_transpose_ab(const float* __restrict__ A,
                                                      const float* __restrict__ B,
                                                      __hip_bfloat16* __restrict__ At,
                                                      __hip_bfloat16* __restrict__ Bt) {
  __shared__ float tile[32][33];
  int x0 = blockIdx.x * 32, y0 = blockIdx.y * 32, z = blockIdx.z;
  const float* src = (z < 16 ? A + (size_t)z * DIM * DIM : B + (size_t)(z - 16) * DIM * DIM);
  __hip_bfloat16* dst = (z < 16 ? At + (size_t)z * DIM * DIM : Bt + (size_t)(z - 16) * DIM * DIM);
  int tx = threadIdx.x, ty = threadIdx.y;
#pragma unroll
  for (int k = 0; k < 4; ++k)
    tile[ty + 8 * k][tx] = src[(size_t)(y0 + ty + 8 * k) * DIM + x0 + tx];
  __syncthreads();
#pragma unroll
  for (int k = 0; k < 4; ++k)
    dst[(size_t)(x0 + ty + 8 * k) * DIM + y0 + tx] = __float2bfloat16(tile[tx][ty + 8 * k]);
}

__global__ __launch_bounds__(256) void k_transpose_u(const float* __restrict__ in,
                                                     __hip_bfloat16* __restrict__ out) {
  __shared__ float tile[32][33];
  int x0 = blockIdx.x * 32, y0 = blockIdx.y * 32;
  int tx = threadIdx.x, ty = threadIdx.y;
#pragma unroll
  for (int k = 0; k < 4; ++k)
    tile[ty + 8 * k][tx] = in[(size_t)(y0 + ty + 8 * k) * DIM + x0 + tx];
  __syncthreads();
#pragma unroll
  for (int k = 0; k < 4; ++k)
    out[(size_t)(x0 + ty + 8 * k) * DIM + y0 + tx] = __float2bfloat16(tile[tx][ty + 8 * k]);
}

// ---- init max buffers to enc(-inf) ----
__global__ void k_init_max(unsigned* p) { p[blockIdx.x * 256 + threadIdx.x] = 0x007FFFFFu; }

// ---- async global->LDS, 16B per lane ----
__device__ __forceinline__ void gload_lds16(const __hip_bfloat16* g, __hip_bfloat16* l) {
  __builtin_amdgcn_global_load_lds(
      (const __attribute__((address_space(1))) uint32_t*)g,
      (__attribute__((address_space(3))) uint32_t*)l, 16, 0, 0);
}

// ---- proj GEMM, M flattened to 8192: Pj[8192][512] = At[8192][512] @ Ut[512][512]^T
__global__ __launch_bounds__(256, 4) void k_proj64(const __hip_bfloat16* __restrict__ At,
                                                   const __hip_bfloat16* __restrict__ Ut,
                                                   __hip_bfloat16* __restrict__ Pj) {
  __shared__ __align__(16) __hip_bfloat16 lA[64 * 64];
  __shared__ __align__(16) __hip_bfloat16 lB[64 * 64];
  const int tid = threadIdx.x, lane = tid & 63, wid = tid >> 6;
  const int wm = wid >> 1, wn = wid & 1;
  const int rowA = blockIdx.x * 64, rowB = blockIdx.y * 64;

  int sl16[2], srow[2], scol[2];
#pragma unroll
  for (int i = 0; i < 2; ++i) {
    int d16 = i * 256 + tid;
    int r = d16 >> 3, p = d16 & 7;
    sl16[i] = d16;
    srow[i] = r;
    scol[i] = (p ^ (r & 7)) * 8;
  }

  f32x4 acc[2][2];
#pragma unroll
  for (int mi = 0; mi < 2; ++mi)
#pragma unroll
    for (int ni = 0; ni < 2; ++ni) acc[mi][ni] = (f32x4){0.f, 0.f, 0.f, 0.f};

  for (int k0 = 0; k0 < DIM; k0 += 64) {
#pragma unroll
    for (int i = 0; i < 2; ++i) {
      gload_lds16(At + (size_t)(rowA + srow[i]) * DIM + k0 + scol[i], &lA[sl16[i] * 8]);
      gload_lds16(Ut + (size_t)(rowB + srow[i]) * DIM + k0 + scol[i], &lB[sl16[i] * 8]);
    }
    __syncthreads();
#pragma unroll
    for (int ks = 0; ks < 2; ++ks) {
      bf16x8 af[2], bfr[2];
#pragma unroll
      for (int mi = 0; mi < 2; ++mi) {
        int r = wm * 32 + mi * 16 + (lane & 15);
        int p = (ks * 4 + (lane >> 4)) ^ (r & 7);
        af[mi] = *(const bf16x8*)&lA[r * 64 + p * 8];
      }
#pragma unroll
      for (int ni = 0; ni < 2; ++ni) {
        int r = wn * 32 + ni * 16 + (lane & 15);
        int p = (ks * 4 + (lane >> 4)) ^ (r & 7);
        bfr[ni] = *(const bf16x8*)&lB[r * 64 + p * 8];
      }
#pragma unroll
      for (int mi = 0; mi < 2; ++mi)
#pragma unroll
        for (int ni = 0; ni < 2; ++ni)
          acc[mi][ni] = __builtin_amdgcn_mfma_f32_16x16x32_bf16(af[mi], bfr[ni], acc[mi][ni], 0, 0, 0);
    }
    __syncthreads();
  }

#pragma unroll
  for (int mi = 0; mi < 2; ++mi) {
    int r0 = rowA + wm * 32 + mi * 16 + ((lane >> 4) << 2);
#pragma unroll
    for (int ni = 0; ni < 2; ++ni) {
      int c = rowB + wn * 32 + ni * 16 + (lane & 15);
#pragma unroll
      for (int j = 0; j < 4; ++j)
        Pj[(size_t)(r0 + j) * DIM + c] = __float2bfloat16(acc[mi][ni][j]);
    }
  }
}

// ---- align GEMM + fused tanh/mask/max epilogue.
// R3 skeleton (dual-b 128x128 tile, 4 waves, 2 blk/CU) + T3-minimum pipeline:
// BK=32, double-buffered LDS (48 KiB), STAGE(t+1) issued BEFORE compute(t),
// one __syncthreads per K-tile (implicit vmcnt(0) drains loads that had the
// whole compute phase to land).
__global__ __launch_bounds__(256, 2) void k_align(const __hip_bfloat16* __restrict__ Pj,
                                                  const __hip_bfloat16* __restrict__ Bt,
                                                  const float* __restrict__ msk,
                                                  unsigned* __restrict__ maxS,
                                                  unsigned* __restrict__ maxT) {
  // [2 bufs][128 rows][32 k] bf16, XOR-swizzled in 16B slots (4 slots/row)
  __shared__ __align__(16) __hip_bfloat16 lA[2 * 128 * 32];
  __shared__ __align__(16) __hip_bfloat16 lB0[2 * 128 * 32];
  __shared__ __align__(16) __hip_bfloat16 lB1[2 * 128 * 32];
  const int tid = threadIdx.x;
  const int lane = tid & 63;
  const int wid = tid >> 6;
  const int wm = wid >> 1, wn = wid & 1;
  const int hi = lane >> 4;

  // bijective decode: xcd = bid&7 owns a in {xcd, xcd+8}
  const int bid = blockIdx.x;
  const int xcd = bid & 7;
  const int slot = bid >> 3;              // [0,256)
  const int a = xcd + 8 * (slot >> 7);    // 2 a's per xcd
  const int rem = slot & 127;             // [0,128)
  const int bp = rem >> 4;                // [0,8): b-pair
  const int x = rem & 15;
  const int bm = x & 3, bn = x >> 2;
  const int b0 = bp * 2, b1 = b0 + 1;

  const int rowA0 = bm * 128, rowB0 = bn * 128;
  const __hip_bfloat16* XA = Pj + (size_t)a * DIM * DIM + (size_t)rowA0 * DIM;
  const __hip_bfloat16* Y0 = Bt + (size_t)b0 * DIM * DIM + (size_t)rowB0 * DIM;
  const __hip_bfloat16* Y1 = Bt + (size_t)b1 * DIM * DIM + (size_t)rowB0 * DIM;

  // staging: thread covers phys 16B slots {tid, tid+256} of the 128x4-slot tile;
  // LDS dest linear, global col pre-XOR-swizzled (involution p^(r&3)).
  int goff[2], loff[2];
#pragma unroll
  for (int i = 0; i < 2; ++i) {
    int d16 = i * 256 + tid;
    int r = d16 >> 2, p = d16 & 3;
    goff[i] = r * DIM + ((p ^ (r & 3)) * 8);
    loff[i] = d16 * 8;
  }

  // fragment LDS element-offsets (within one 4096-elem buffer)
  int fA[4], fB[4];
#pragma unroll
  for (int mi = 0; mi < 4; ++mi) {
    int r = wm * 64 + mi * 16 + (lane & 15);
    fA[mi] = r * 32 + ((hi ^ (r & 3)) * 8);
  }
#pragma unroll
  for (int ni = 0; ni < 4; ++ni) {
    int r = wn * 64 + ni * 16 + (lane & 15);
    fB[ni] = r * 32 + ((hi ^ (r & 3)) * 8);
  }

  f32x4 acc0[4][4], acc1[4][4];
#pragma unroll
  for (int mi = 0; mi < 4; ++mi)
#pragma unroll
    for (int ni = 0; ni < 4; ++ni) {
      acc0[mi][ni] = (f32x4){0.f, 0.f, 0.f, 0.f};
      acc1[mi][ni] = (f32x4){0.f, 0.f, 0.f, 0.f};
    }

#define STAGE(kt, c)                                                         \
  {                                                                          \
    _Pragma("unroll") for (int i = 0; i < 2; ++i) {                          \
      gload_lds16(XA + goff[i] + (kt)*32, &lA[(c)*4096 + loff[i]]);          \
      gload_lds16(Y0 + goff[i] + (kt)*32, &lB0[(c)*4096 + loff[i]]);         \
      gload_lds16(Y1 + goff[i] + (kt)*32, &lB1[(c)*4096 + loff[i]]);         \
    }                                                                        \
  }

  STAGE(0, 0);
  __syncthreads();

  for (int t = 0; t < 16; ++t) {
    const int c = t & 1;
    if (t < 15) STAGE(t + 1, c ^ 1);  // prefetch next tile; lands during compute
    bf16x8 af[4], bv0[4], bv1[4];
#pragma unroll
    for (int mi = 0; mi < 4; ++mi) af[mi] = *(const bf16x8*)&lA[c * 4096 + fA[mi]];
#pragma unroll
    for (int ni = 0; ni < 4; ++ni) {
      bv0[ni] = *(const bf16x8*)&lB0[c * 4096 + fB[ni]];
      bv1[ni] = *(const bf16x8*)&lB1[c * 4096 + fB[ni]];
    }
#pragma unroll
    for (int mi = 0; mi < 4; ++mi)
#pragma unroll
      for (int ni = 0; ni < 4; ++ni) {
        acc0[mi][ni] = __builtin_amdgcn_mfma_f32_16x16x32_bf16(af[mi], bv0[ni], acc0[mi][ni], 0, 0, 0);
        acc1[mi][ni] = __builtin_amdgcn_mfma_f32_16x16x32_bf16(af[mi], bv1[ni], acc1[mi][ni], 0, 0, 0);
      }
    __syncthreads();  // drains t+1's 6 loads (vmcnt0) + guards buf reuse
  }
#undef STAGE

  // ---- epilogue: tanh + mask (loaded once, reused for both b) + row/col max
  const float* mk = msk + (size_t)a * DIM * DIM;
  float rmx0[4][4], rmx1[4][4], cmx0[4], cmx1[4];
#pragma unroll
  for (int mi = 0; mi < 4; ++mi)
#pragma unroll
    for (int j = 0; j < 4; ++j) { rmx0[mi][j] = -INFINITY; rmx1[mi][j] = -INFINITY; }
#pragma unroll
  for (int ni = 0; ni < 4; ++ni) { cmx0[ni] = -INFINITY; cmx1[ni] = -INFINITY; }

#pragma unroll
  for (int mi = 0; mi < 4; ++mi) {
    int s0 = rowA0 + wm * 64 + mi * 16 + hi * 4;
#pragma unroll
    for (int ni = 0; ni < 4; ++ni) {
      int t = rowB0 + wn * 64 + ni * 16 + (lane & 15);
#pragma unroll
      for (int j = 0; j < 4; ++j) {
        float m = mk[(size_t)(s0 + j) * DIM + t];
        float v0 = tanh_fast(acc0[mi][ni][j]) + m;
        float v1 = tanh_fast(acc1[mi][ni][j]) + m;
        rmx0[mi][j] = fmaxf(rmx0[mi][j], v0);
        rmx1[mi][j] = fmaxf(rmx1[mi][j], v1);
        cmx0[ni] = fmaxf(cmx0[ni], v0);
        cmx1[ni] = fmaxf(cmx1[ni], v1);
      }
    }
  }

  const int pr0 = a * 16 + b0, pr1 = a * 16 + b1;
#pragma unroll
  for (int mi = 0; mi < 4; ++mi)
#pragma unroll
    for (int j = 0; j < 4; ++j) {
      float r0 = rmx0[mi][j], r1 = rmx1[mi][j];
      r0 = fmaxf(r0, __shfl_xor(r0, 1));
      r0 = fmaxf(r0, __shfl_xor(r0, 2));
      r0 = fmaxf(r0, __shfl_xor(r0, 4));
      r0 = fmaxf(r0, __shfl_xor(r0, 8));
      r1 = fmaxf(r1, __shfl_xor(r1, 1));
      r1 = fmaxf(r1, __shfl_xor(r1, 2));
      r1 = fmaxf(r1, __shfl_xor(r1, 4));
      r1 = fmaxf(r1, __shfl_xor(r1, 8));
      if ((lane & 15) == 0) {
        int s = rowA0 + wm * 64 + mi * 16 + hi * 4 + j;
        atomicMax(&maxS[(size_t)pr0 * DIM + s], fenc(r0));
        atomicMax(&maxS[(size_t)pr1 * DIM + s], fenc(r1));
      }
    }
#pragma unroll
  for (int ni = 0; ni < 4; ++ni) {
    float c0 = cmx0[ni], c1 = cmx1[ni];
    c0 = fmaxf(c0, __shfl_xor(c0, 16));
    c0 = fmaxf(c0, __shfl_xor(c0, 32));
    c1 = fmaxf(c1, __shfl_xor(c1, 16));
    c1 = fmaxf(c1, __shfl_xor(c1, 32));
    if (lane < 16) {
      int t = rowB0 + wn * 64 + ni * 16 + lane;
      atomicMax(&maxT[(size_t)pr0 * DIM + t], fenc(c0));
      atomicMax(&maxT[(size_t)pr1 * DIM + t], fenc(c1));
    }
  }
}

// ---- softmax over the 512 max-logits of each (pair, side) ----
__global__ __launch_bounds__(64) void k_softmax(const unsigned* __restrict__ menc,
                                                float* __restrict__ sc) {
  int pair = blockIdx.x, side = blockIdx.y;
  const unsigned* buf = menc + (size_t)side * 256 * DIM + (size_t)pair * DIM;
  float* out = sc + (size_t)side * 256 * DIM + (size_t)pair * DIM;
  int lane = threadIdx.x;
  float v[8];
  float m = -INFINITY;
#pragma unroll
  for (int k = 0; k < 8; ++k) {
    v[k] = fdec(buf[lane + 64 * k]);
    m = fmaxf(m, v[k]);
  }
#pragma unroll
  for (int off = 1; off < 64; off <<= 1) m = fmaxf(m, __shfl_xor(m, off));
  float s = 0.f;
#pragma unroll
  for (int k = 0; k < 8; ++k) {
    v[k] = expf(v[k] - m);
    s += v[k];
  }
#pragma unroll
  for (int off = 1; off < 64; off <<= 1) s += __shfl_xor(s, off);
  float inv = 1.0f / s;
#pragma unroll
  for (int k = 0; k < 8; ++k) out[lane + 64 * k] = v[k] * inv;
}

// ---- attention-weighted pooling: out[pair][d] = sum_s mat[d][s] * score[pair][s]
__global__ __launch_bounds__(256) void k_pool(const float* __restrict__ A,
                                              const float* __restrict__ B,
                                              const float* __restrict__ sc,
                                              float* __restrict__ out) {
  __shared__ float ta[128][65];
  __shared__ float ts[16][128];
  int t = threadIdx.x;
  int d0 = blockIdx.x * 64;
  int y = blockIdx.y, side = blockIdx.z;
  const float* mat = (side ? B : A) + (size_t)y * DIM * DIM;
  const float* scb = sc + (size_t)side * 256 * DIM;
  float* ob = out + (size_t)side * 256 * DIM;
  int dl = t & 63, g = t >> 6;
  float acc[4] = {0.f, 0.f, 0.f, 0.f};
  for (int st = 0; st < 4; ++st) {
    __syncthreads();
#pragma unroll
    for (int i = 0; i < 32; ++i) {
      int idx = t + 256 * i;
      int r = idx >> 7, c = idx & 127;
      ta[c][r] = mat[(size_t)(d0 + r) * DIM + st * 128 + c];
    }
#pragma unroll
    for (int i = 0; i < 8; ++i) {
      int idx = t + 256 * i;
      int p = idx >> 7, s = idx & 127;
      int pair = side ? (p * 16 + y) : (y * 16 + p);
      ts[p][s] = scb[(size_t)pair * DIM + st * 128 + s];
    }
    __syncthreads();
    for (int s = 0; s < 128; ++s) {
      float v = ta[s][dl];
#pragma unroll
      for (int i = 0; i < 4; ++i) acc[i] += v * ts[g * 4 + i][s];
    }
  }
#pragma unroll
  for (int i = 0; i < 4; ++i) {
    int p = g * 4 + i;
    int pair = side ? (p * 16 + y) : (y * 16 + p);
    ob[(size_t)pair * DIM + d0 + dl] = acc[i];
  }
}

extern "C" void kernel_launch(void* const* d_in, const int* in_sizes, int n_in,
                              void* d_out, int out_size, void* d_ws, size_t ws_size,
                              hipStream_t stream) {
  (void)in_sizes; (void)n_in; (void)out_size; (void)ws_size;
  const float* A = (const float*)d_in[0];    // (16, 512, 512) d-major
  const float* B = (const float*)d_in[1];    // (16, 512, 512) d-major
  const float* msk = (const float*)d_in[2];  // (16, 512, 512)
  const float* U = (const float*)d_in[3];    // (512, 512)

  char* w = (char*)d_ws;
  __hip_bfloat16* At = (__hip_bfloat16*)(w + 0);         //  8 MB: [a][s][d] == [8192][512]
  __hip_bfloat16* Bt = (__hip_bfloat16*)(w + 8388608);   //  8 MB: [b][t][e]
  __hip_bfloat16* Ut = (__hip_bfloat16*)(w + 16777216);  //  512 KB: [e][d]
  __hip_bfloat16* Pj = (__hip_bfloat16*)(w + 17301504);  //  8 MB: [a][s][e] == [8192][512]
  unsigned* menc = (unsigned*)(w + 25690112);            //  1 MB: maxS | maxT
  float* sc = (float*)(w + 26738688);                    //  1 MB: scores
  unsigned* maxS = menc;
  unsigned* maxT = menc + 256 * DIM;

  k_transpose_ab<<<dim3(16, 16, 32), dim3(32, 8), 0, stream>>>(A, B, At, Bt);
  k_transpose_u<<<dim3(16, 16), dim3(32, 8), 0, stream>>>(U, Ut);
  k_init_max<<<1024, 256, 0, stream>>>(menc);
  k_proj64<<<dim3(128, 8), 256, 0, stream>>>(At, Ut, Pj);
  k_align<<<2048, 256, 0, stream>>>(Pj, Bt, msk, maxS, maxT);
  k_softmax<<<dim3(256, 2), 64, 0, stream>>>(menc, sc);
  k_pool<<<dim3(8, 16, 2), 256, 0, stream>>>(A, B, sc, (float*)d_out);
}

// Round 6
// 199.068 us; speedup vs baseline: 1.0153x; 1.0071x over previous
//
#include <hip/hip_runtime.h>
#include <hip/hip_bf16.h>
#include <stdint.h>

#define DIM 512

typedef __bf16 bf16x8 __attribute__((ext_vector_type(8)));
typedef float f32x4 __attribute__((ext_vector_type(4)));

// ---- monotonic float<->uint encoding for atomicMax on signed floats ----
__device__ __forceinline__ unsigned fenc(float f) {
  unsigned u = __float_as_uint(f);
  return (u & 0x80000000u) ? ~u : (u | 0x80000000u);
}
__device__ __forceinline__ float fdec(unsigned e) {
  unsigned u = (e & 0x80000000u) ? (e & 0x7FFFFFFFu) : ~e;
  return __uint_as_float(u);
}

// ---- fast tanh: 1 - 2/(exp(2x)+1). ~5 VALU ops, exact at saturated tails.
__device__ __forceinline__ float tanh_fast(float x) {
  float e = __expf(2.0f * x);
  return 1.0f - 2.0f * __builtin_amdgcn_rcpf(e + 1.0f);
}

// ---- transpose last-2-dims + f32->bf16; z<16: A->At, z>=16: B->Bt ----
__global__ __launch_bounds__(256) void k_transpose_ab(const float* __restrict__ A,
                                                      const float* __restrict__ B,
                                                      __hip_bfloat16* __restrict__ At,
                                                      __hip_bfloat16* __restrict__ Bt) {
  __shared__ float tile[32][33];
  int x0 = blockIdx.x * 32, y0 = blockIdx.y * 32, z = blockIdx.z;
  const float* src = (z < 16 ? A + (size_t)z * DIM * DIM : B + (size_t)(z - 16) * DIM * DIM);
  __hip_bfloat16* dst = (z < 16 ? At + (size_t)z * DIM * DIM : Bt + (size_t)(z - 16) * DIM * DIM);
  int tx = threadIdx.x, ty = threadIdx.y;
#pragma unroll
  for (int k = 0; k < 4; ++k)
    tile[ty + 8 * k][tx] = src[(size_t)(y0 + ty + 8 * k) * DIM + x0 + tx];
  __syncthreads();
#pragma unroll
  for (int k = 0; k < 4; ++k)
    dst[(size_t)(x0 + ty + 8 * k) * DIM + y0 + tx] = __float2bfloat16(tile[tx][ty + 8 * k]);
}

__global__ __launch_bounds__(256) void k_transpose_u(const float* __restrict__ in,
                                                     __hip_bfloat16* __restrict__ out) {
  __shared__ float tile[32][33];
  int x0 = blockIdx.x * 32, y0 = blockIdx.y * 32;
  int tx = threadIdx.x, ty = threadIdx.y;
#pragma unroll
  for (int k = 0; k < 4; ++k)
    tile[ty + 8 * k][tx] = in[(size_t)(y0 + ty + 8 * k) * DIM + x0 + tx];
  __syncthreads();
#pragma unroll
  for (int k = 0; k < 4; ++k)
    out[(size_t)(x0 + ty + 8 * k) * DIM + y0 + tx] = __float2bfloat16(tile[tx][ty + 8 * k]);
}

// ---- init max buffers to enc(-inf) ----
__global__ void k_init_max(unsigned* p) { p[blockIdx.x * 256 + threadIdx.x] = 0x007FFFFFu; }

// ---- async global->LDS, 16B per lane ----
__device__ __forceinline__ void gload_lds16(const __hip_bfloat16* g, __hip_bfloat16* l) {
  __builtin_amdgcn_global_load_lds(
      (const __attribute__((address_space(1))) uint32_t*)g,
      (__attribute__((address_space(3))) uint32_t*)l, 16, 0, 0);
}

// ---- proj GEMM, M flattened to 8192: Pj[8192][512] = At[8192][512] @ Ut[512][512]^T
__global__ __launch_bounds__(256, 4) void k_proj64(const __hip_bfloat16* __restrict__ At,
                                                   const __hip_bfloat16* __restrict__ Ut,
                                                   __hip_bfloat16* __restrict__ Pj) {
  __shared__ __align__(16) __hip_bfloat16 lA[64 * 64];
  __shared__ __align__(16) __hip_bfloat16 lB[64 * 64];
  const int tid = threadIdx.x, lane = tid & 63, wid = tid >> 6;
  const int wm = wid >> 1, wn = wid & 1;
  const int rowA = blockIdx.x * 64, rowB = blockIdx.y * 64;

  int sl16[2], srow[2], scol[2];
#pragma unroll
  for (int i = 0; i < 2; ++i) {
    int d16 = i * 256 + tid;
    int r = d16 >> 3, p = d16 & 7;
    sl16[i] = d16;
    srow[i] = r;
    scol[i] = (p ^ (r & 7)) * 8;
  }

  f32x4 acc[2][2];
#pragma unroll
  for (int mi = 0; mi < 2; ++mi)
#pragma unroll
    for (int ni = 0; ni < 2; ++ni) acc[mi][ni] = (f32x4){0.f, 0.f, 0.f, 0.f};

  for (int k0 = 0; k0 < DIM; k0 += 64) {
#pragma unroll
    for (int i = 0; i < 2; ++i) {
      gload_lds16(At + (size_t)(rowA + srow[i]) * DIM + k0 + scol[i], &lA[sl16[i] * 8]);
      gload_lds16(Ut + (size_t)(rowB + srow[i]) * DIM + k0 + scol[i], &lB[sl16[i] * 8]);
    }
    __syncthreads();
#pragma unroll
    for (int ks = 0; ks < 2; ++ks) {
      bf16x8 af[2], bfr[2];
#pragma unroll
      for (int mi = 0; mi < 2; ++mi) {
        int r = wm * 32 + mi * 16 + (lane & 15);
        int p = (ks * 4 + (lane >> 4)) ^ (r & 7);
        af[mi] = *(const bf16x8*)&lA[r * 64 + p * 8];
      }
#pragma unroll
      for (int ni = 0; ni < 2; ++ni) {
        int r = wn * 32 + ni * 16 + (lane & 15);
        int p = (ks * 4 + (lane >> 4)) ^ (r & 7);
        bfr[ni] = *(const bf16x8*)&lB[r * 64 + p * 8];
      }
#pragma unroll
      for (int mi = 0; mi < 2; ++mi)
#pragma unroll
        for (int ni = 0; ni < 2; ++ni)
          acc[mi][ni] = __builtin_amdgcn_mfma_f32_16x16x32_bf16(af[mi], bfr[ni], acc[mi][ni], 0, 0, 0);
    }
    __syncthreads();
  }

#pragma unroll
  for (int mi = 0; mi < 2; ++mi) {
    int r0 = rowA + wm * 32 + mi * 16 + ((lane >> 4) << 2);
#pragma unroll
    for (int ni = 0; ni < 2; ++ni) {
      int c = rowB + wn * 32 + ni * 16 + (lane & 15);
#pragma unroll
      for (int j = 0; j < 4; ++j)
        Pj[(size_t)(r0 + j) * DIM + c] = __float2bfloat16(acc[mi][ni][j]);
    }
  }
}

// ---- align GEMM + fused tanh/mask/max epilogue.
// Dual-b 128x128 tile, 4 waves, BK=32 double-buffered (48 KiB), STAGE(t+1)
// issued BEFORE compute(t), one __syncthreads per K-tile.
// LDS swizzle: phys slot p holds logical k-slot p ^ ((r>>1)&3).
// Per-16-lane-phase conflict check: granule-group = 4*(r&1) + (hi^((r>>1)&3))
// covers all 8 groups exactly 2x -> 2-way = free (R5's r&3 gave 4-way, 6.3M conflicts).
__global__ __launch_bounds__(256, 2) void k_align(const __hip_bfloat16* __restrict__ Pj,
                                                  const __hip_bfloat16* __restrict__ Bt,
                                                  const float* __restrict__ msk,
                                                  unsigned* __restrict__ maxS,
                                                  unsigned* __restrict__ maxT) {
  __shared__ __align__(16) __hip_bfloat16 lA[2 * 128 * 32];
  __shared__ __align__(16) __hip_bfloat16 lB0[2 * 128 * 32];
  __shared__ __align__(16) __hip_bfloat16 lB1[2 * 128 * 32];
  const int tid = threadIdx.x;
  const int lane = tid & 63;
  const int wid = tid >> 6;
  const int wm = wid >> 1, wn = wid & 1;
  const int hi = lane >> 4;

  // bijective decode: xcd = bid&7 owns a in {xcd, xcd+8}
  const int bid = blockIdx.x;
  const int xcd = bid & 7;
  const int slot = bid >> 3;              // [0,256)
  const int a = xcd + 8 * (slot >> 7);    // 2 a's per xcd
  const int rem = slot & 127;             // [0,128)
  const int bp = rem >> 4;                // [0,8): b-pair
  const int x = rem & 15;
  const int bm = x & 3, bn = x >> 2;
  const int b0 = bp * 2, b1 = b0 + 1;

  const int rowA0 = bm * 128, rowB0 = bn * 128;
  const __hip_bfloat16* XA = Pj + (size_t)a * DIM * DIM + (size_t)rowA0 * DIM;
  const __hip_bfloat16* Y0 = Bt + (size_t)b0 * DIM * DIM + (size_t)rowB0 * DIM;
  const __hip_bfloat16* Y1 = Bt + (size_t)b1 * DIM * DIM + (size_t)rowB0 * DIM;

  // staging: thread covers phys 16B slots {tid, tid+256}; LDS dest linear,
  // global source col pre-swizzled with the involution p ^ ((r>>1)&3).
  int goff[2], loff[2];
#pragma unroll
  for (int i = 0; i < 2; ++i) {
    int d16 = i * 256 + tid;
    int r = d16 >> 2, p = d16 & 3;
    goff[i] = r * DIM + ((p ^ ((r >> 1) & 3)) * 8);
    loff[i] = d16 * 8;
  }

  // fragment LDS element-offsets (within one 4096-elem buffer)
  int fA[4], fB[4];
#pragma unroll
  for (int mi = 0; mi < 4; ++mi) {
    int r = wm * 64 + mi * 16 + (lane & 15);
    fA[mi] = r * 32 + ((hi ^ ((r >> 1) & 3)) * 8);
  }
#pragma unroll
  for (int ni = 0; ni < 4; ++ni) {
    int r = wn * 64 + ni * 16 + (lane & 15);
    fB[ni] = r * 32 + ((hi ^ ((r >> 1) & 3)) * 8);
  }

  f32x4 acc0[4][4], acc1[4][4];
#pragma unroll
  for (int mi = 0; mi < 4; ++mi)
#pragma unroll
    for (int ni = 0; ni < 4; ++ni) {
      acc0[mi][ni] = (f32x4){0.f, 0.f, 0.f, 0.f};
      acc1[mi][ni] = (f32x4){0.f, 0.f, 0.f, 0.f};
    }

#define STAGE(kt, c)                                                         \
  {                                                                          \
    _Pragma("unroll") for (int i = 0; i < 2; ++i) {                          \
      gload_lds16(XA + goff[i] + (kt)*32, &lA[(c)*4096 + loff[i]]);          \
      gload_lds16(Y0 + goff[i] + (kt)*32, &lB0[(c)*4096 + loff[i]]);         \
      gload_lds16(Y1 + goff[i] + (kt)*32, &lB1[(c)*4096 + loff[i]]);         \
    }                                                                        \
  }

  STAGE(0, 0);
  __syncthreads();

  for (int t = 0; t < 16; ++t) {
    const int c = t & 1;
    if (t < 15) STAGE(t + 1, c ^ 1);  // prefetch next tile; lands during compute
    bf16x8 af[4], bv0[4], bv1[4];
#pragma unroll
    for (int mi = 0; mi < 4; ++mi) af[mi] = *(const bf16x8*)&lA[c * 4096 + fA[mi]];
#pragma unroll
    for (int ni = 0; ni < 4; ++ni) {
      bv0[ni] = *(const bf16x8*)&lB0[c * 4096 + fB[ni]];
      bv1[ni] = *(const bf16x8*)&lB1[c * 4096 + fB[ni]];
    }
#pragma unroll
    for (int mi = 0; mi < 4; ++mi)
#pragma unroll
      for (int ni = 0; ni < 4; ++ni) {
        acc0[mi][ni] = __builtin_amdgcn_mfma_f32_16x16x32_bf16(af[mi], bv0[ni], acc0[mi][ni], 0, 0, 0);
        acc1[mi][ni] = __builtin_amdgcn_mfma_f32_16x16x32_bf16(af[mi], bv1[ni], acc1[mi][ni], 0, 0, 0);
      }
    __syncthreads();  // drains t+1's 6 loads + guards buf reuse
  }
#undef STAGE

  // ---- epilogue: tanh + mask (loaded once, reused for both b) + row/col max
  const float* mk = msk + (size_t)a * DIM * DIM;
  float rmx0[4][4], rmx1[4][4], cmx0[4], cmx1[4];
#pragma unroll
  for (int mi = 0; mi < 4; ++mi)
#pragma unroll
    for (int j = 0; j < 4; ++j) { rmx0[mi][j] = -INFINITY; rmx1[mi][j] = -INFINITY; }
#pragma unroll
  for (int ni = 0; ni < 4; ++ni) { cmx0[ni] = -INFINITY; cmx1[ni] = -INFINITY; }

#pragma unroll
  for (int mi = 0; mi < 4; ++mi) {
    int s0 = rowA0 + wm * 64 + mi * 16 + hi * 4;
#pragma unroll
    for (int ni = 0; ni < 4; ++ni) {
      int t = rowB0 + wn * 64 + ni * 16 + (lane & 15);
#pragma unroll
      for (int j = 0; j < 4; ++j) {
        float m = mk[(size_t)(s0 + j) * DIM + t];
        float v0 = tanh_fast(acc0[mi][ni][j]) + m;
        float v1 = tanh_fast(acc1[mi][ni][j]) + m;
        rmx0[mi][j] = fmaxf(rmx0[mi][j], v0);
        rmx1[mi][j] = fmaxf(rmx1[mi][j], v1);
        cmx0[ni] = fmaxf(cmx0[ni], v0);
        cmx1[ni] = fmaxf(cmx1[ni], v1);
      }
    }
  }

  const int pr0 = a * 16 + b0, pr1 = a * 16 + b1;
#pragma unroll
  for (int mi = 0; mi < 4; ++mi)
#pragma unroll
    for (int j = 0; j < 4; ++j) {
      float r0 = rmx0[mi][j], r1 = rmx1[mi][j];
      r0 = fmaxf(r0, __shfl_xor(r0, 1));
      r0 = fmaxf(r0, __shfl_xor(r0, 2));
      r0 = fmaxf(r0, __shfl_xor(r0, 4));
      r0 = fmaxf(r0, __shfl_xor(r0, 8));
      r1 = fmaxf(r1, __shfl_xor(r1, 1));
      r1 = fmaxf(r1, __shfl_xor(r1, 2));
      r1 = fmaxf(r1, __shfl_xor(r1, 4));
      r1 = fmaxf(r1, __shfl_xor(r1, 8));
      if ((lane & 15) == 0) {
        int s = rowA0 + wm * 64 + mi * 16 + hi * 4 + j;
        atomicMax(&maxS[(size_t)pr0 * DIM + s], fenc(r0));
        atomicMax(&maxS[(size_t)pr1 * DIM + s], fenc(r1));
      }
    }
#pragma unroll
  for (int ni = 0; ni < 4; ++ni) {
    float c0 = cmx0[ni], c1 = cmx1[ni];
    c0 = fmaxf(c0, __shfl_xor(c0, 16));
    c0 = fmaxf(c0, __shfl_xor(c0, 32));
    c1 = fmaxf(c1, __shfl_xor(c1, 16));
    c1 = fmaxf(c1, __shfl_xor(c1, 32));
    if (lane < 16) {
      int t = rowB0 + wn * 64 + ni * 16 + lane;
      atomicMax(&maxT[(size_t)pr0 * DIM + t], fenc(c0));
      atomicMax(&maxT[(size_t)pr1 * DIM + t], fenc(c1));
    }
  }
}

// ---- softmax over the 512 max-logits of each (pair, side) ----
__global__ __launch_bounds__(64) void k_softmax(const unsigned* __restrict__ menc,
                                                float* __restrict__ sc) {
  int pair = blockIdx.x, side = blockIdx.y;
  const unsigned* buf = menc + (size_t)side * 256 * DIM + (size_t)pair * DIM;
  float* out = sc + (size_t)side * 256 * DIM + (size_t)pair * DIM;
  int lane = threadIdx.x;
  float v[8];
  float m = -INFINITY;
#pragma unroll
  for (int k = 0; k < 8; ++k) {
    v[k] = fdec(buf[lane + 64 * k]);
    m = fmaxf(m, v[k]);
  }
#pragma unroll
  for (int off = 1; off < 64; off <<= 1) m = fmaxf(m, __shfl_xor(m, off));
  float s = 0.f;
#pragma unroll
  for (int k = 0; k < 8; ++k) {
    v[k] = expf(v[k] - m);
    s += v[k];
  }
#pragma unroll
  for (int off = 1; off < 64; off <<= 1) s += __shfl_xor(s, off);
  float inv = 1.0f / s;
#pragma unroll
  for (int k = 0; k < 8; ++k) out[lane + 64 * k] = v[k] * inv;
}

// ---- attention-weighted pooling: out[pair][d] = sum_s mat[d][s] * score[pair][s]
__global__ __launch_bounds__(256) void k_pool(const float* __restrict__ A,
                                              const float* __restrict__ B,
                                              const float* __restrict__ sc,
                                              float* __restrict__ out) {
  __shared__ float ta[128][65];
  __shared__ float ts[16][128];
  int t = threadIdx.x;
  int d0 = blockIdx.x * 64;
  int y = blockIdx.y, side = blockIdx.z;
  const float* mat = (side ? B : A) + (size_t)y * DIM * DIM;
  const float* scb = sc + (size_t)side * 256 * DIM;
  float* ob = out + (size_t)side * 256 * DIM;
  int dl = t & 63, g = t >> 6;
  float acc[4] = {0.f, 0.f, 0.f, 0.f};
  for (int st = 0; st < 4; ++st) {
    __syncthreads();
#pragma unroll
    for (int i = 0; i < 32; ++i) {
      int idx = t + 256 * i;
      int r = idx >> 7, c = idx & 127;
      ta[c][r] = mat[(size_t)(d0 + r) * DIM + st * 128 + c];
    }
#pragma unroll
    for (int i = 0; i < 8; ++i) {
      int idx = t + 256 * i;
      int p = idx >> 7, s = idx & 127;
      int pair = side ? (p * 16 + y) : (y * 16 + p);
      ts[p][s] = scb[(size_t)pair * DIM + st * 128 + s];
    }
    __syncthreads();
    for (int s = 0; s < 128; ++s) {
      float v = ta[s][dl];
#pragma unroll
      for (int i = 0; i < 4; ++i) acc[i] += v * ts[g * 4 + i][s];
    }
  }
#pragma unroll
  for (int i = 0; i < 4; ++i) {
    int p = g * 4 + i;
    int pair = side ? (p * 16 + y) : (y * 16 + p);
    ob[(size_t)pair * DIM + d0 + dl] = acc[i];
  }
}

extern "C" void kernel_launch(void* const* d_in, const int* in_sizes, int n_in,
                              void* d_out, int out_size, void* d_ws, size_t ws_size,
                              hipStream_t stream) {
  (void)in_sizes; (void)n_in; (void)out_size; (void)ws_size;
  const float* A = (const float*)d_in[0];    // (16, 512, 512) d-major
  const float* B = (const float*)d_in[1];    // (16, 512, 512) d-major
  const float* msk = (const float*)d_in[2];  // (16, 512, 512)
  const float* U = (const float*)d_in[3];    // (512, 512)

  char* w = (char*)d_ws;
  __hip_bfloat16* At = (__hip_bfloat16*)(w + 0);         //  8 MB: [a][s][d] == [8192][512]
  __hip_bfloat16* Bt = (__hip_bfloat16*)(w + 8388608);   //  8 MB: [b][t][e]
  __hip_bfloat16* Ut = (__hip_bfloat16*)(w + 16777216);  //  512 KB: [e][d]
  __hip_bfloat16* Pj = (__hip_bfloat16*)(w + 17301504);  //  8 MB: [a][s][e] == [8192][512]
  unsigned* menc = (unsigned*)(w + 25690112);            //  1 MB: maxS | maxT
  float* sc = (float*)(w + 26738688);                    //  1 MB: scores
  unsigned* maxS = menc;
  unsigned* maxT = menc + 256 * DIM;

  k_transpose_ab<<<dim3(16, 16, 32), dim3(32, 8), 0, stream>>>(A, B, At, Bt);
  k_transpose_u<<<dim3(16, 16), dim3(32, 8), 0, stream>>>(U, Ut);
  k_init_max<<<1024, 256, 0, stream>>>(menc);
  k_proj64<<<dim3(128, 8), 256, 0, stream>>>(At, Ut, Pj);
  k_align<<<2048, 256, 0, stream>>>(Pj, Bt, msk, maxS, maxT);
  k_softmax<<<dim3(256, 2), 64, 0, stream>>>(menc, sc);
  k_pool<<<dim3(8, 16, 2), 256, 0, stream>>>(A, B, sc, (float*)d_out);
}

// Round 7
// 193.649 us; speedup vs baseline: 1.0437x; 1.0280x over previous
//
#include <hip/hip_runtime.h>
#include <hip/hip_bf16.h>
#include <stdint.h>

#define DIM 512

typedef __bf16 bf16x8 __attribute__((ext_vector_type(8)));
typedef float f32x4 __attribute__((ext_vector_type(4)));

// ---- monotonic float<->uint encoding for atomicMax on signed floats ----
__device__ __forceinline__ unsigned fenc(float f) {
  unsigned u = __float_as_uint(f);
  return (u & 0x80000000u) ? ~u : (u | 0x80000000u);
}
__device__ __forceinline__ float fdec(unsigned e) {
  unsigned u = (e & 0x80000000u) ? (e & 0x7FFFFFFFu) : ~e;
  return __uint_as_float(u);
}

// ---- fast tanh: 1 - 2/(exp(2x)+1). ~5 VALU ops, exact at saturated tails.
__device__ __forceinline__ float tanh_fast(float x) {
  float e = __expf(2.0f * x);
  return 1.0f - 2.0f * __builtin_amdgcn_rcpf(e + 1.0f);
}

// ---- prep: z<32 transpose A/B +convert; z==32 transpose U; z==33 init max ----
__global__ __launch_bounds__(256) void k_prep(const float* __restrict__ A,
                                              const float* __restrict__ B,
                                              const float* __restrict__ U,
                                              __hip_bfloat16* __restrict__ At,
                                              __hip_bfloat16* __restrict__ Bt,
                                              __hip_bfloat16* __restrict__ Ut,
                                              unsigned* __restrict__ menc) {
  int z = blockIdx.z;
  int tx = threadIdx.x, ty = threadIdx.y;
  if (z == 33) {
    int gid = (blockIdx.y * 16 + blockIdx.x) * 256 + ty * 32 + tx;
#pragma unroll
    for (int k = 0; k < 4; ++k) menc[gid + 65536 * k] = 0x007FFFFFu;  // enc(-inf)
    return;
  }
  __shared__ float tile[32][33];
  int x0 = blockIdx.x * 32, y0 = blockIdx.y * 32;
  const float* src;
  __hip_bfloat16* dst;
  if (z == 32) {
    src = U;
    dst = Ut;
  } else if (z < 16) {
    src = A + (size_t)z * DIM * DIM;
    dst = At + (size_t)z * DIM * DIM;
  } else {
    src = B + (size_t)(z - 16) * DIM * DIM;
    dst = Bt + (size_t)(z - 16) * DIM * DIM;
  }
#pragma unroll
  for (int k = 0; k < 4; ++k)
    tile[ty + 8 * k][tx] = src[(size_t)(y0 + ty + 8 * k) * DIM + x0 + tx];
  __syncthreads();
#pragma unroll
  for (int k = 0; k < 4; ++k)
    dst[(size_t)(x0 + ty + 8 * k) * DIM + y0 + tx] = __float2bfloat16(tile[tx][ty + 8 * k]);
}

// ---- async global->LDS, 16B per lane ----
__device__ __forceinline__ void gload_lds16(const __hip_bfloat16* g, __hip_bfloat16* l) {
  __builtin_amdgcn_global_load_lds(
      (const __attribute__((address_space(1))) uint32_t*)g,
      (__attribute__((address_space(3))) uint32_t*)l, 16, 0, 0);
}

// ---- proj GEMM, M flattened to 8192: Pj[8192][512] = At[8192][512] @ Ut[512][512]^T
__global__ __launch_bounds__(256, 4) void k_proj64(const __hip_bfloat16* __restrict__ At,
                                                   const __hip_bfloat16* __restrict__ Ut,
                                                   __hip_bfloat16* __restrict__ Pj) {
  __shared__ __align__(16) __hip_bfloat16 lA[64 * 64];
  __shared__ __align__(16) __hip_bfloat16 lB[64 * 64];
  const int tid = threadIdx.x, lane = tid & 63, wid = tid >> 6;
  const int wm = wid >> 1, wn = wid & 1;
  const int rowA = blockIdx.x * 64, rowB = blockIdx.y * 64;

  int sl16[2], srow[2], scol[2];
#pragma unroll
  for (int i = 0; i < 2; ++i) {
    int d16 = i * 256 + tid;
    int r = d16 >> 3, p = d16 & 7;
    sl16[i] = d16;
    srow[i] = r;
    scol[i] = (p ^ (r & 7)) * 8;
  }

  f32x4 acc[2][2];
#pragma unroll
  for (int mi = 0; mi < 2; ++mi)
#pragma unroll
    for (int ni = 0; ni < 2; ++ni) acc[mi][ni] = (f32x4){0.f, 0.f, 0.f, 0.f};

  for (int k0 = 0; k0 < DIM; k0 += 64) {
#pragma unroll
    for (int i = 0; i < 2; ++i) {
      gload_lds16(At + (size_t)(rowA + srow[i]) * DIM + k0 + scol[i], &lA[sl16[i] * 8]);
      gload_lds16(Ut + (size_t)(rowB + srow[i]) * DIM + k0 + scol[i], &lB[sl16[i] * 8]);
    }
    __syncthreads();
#pragma unroll
    for (int ks = 0; ks < 2; ++ks) {
      bf16x8 af[2], bfr[2];
#pragma unroll
      for (int mi = 0; mi < 2; ++mi) {
        int r = wm * 32 + mi * 16 + (lane & 15);
        int p = (ks * 4 + (lane >> 4)) ^ (r & 7);
        af[mi] = *(const bf16x8*)&lA[r * 64 + p * 8];
      }
#pragma unroll
      for (int ni = 0; ni < 2; ++ni) {
        int r = wn * 32 + ni * 16 + (lane & 15);
        int p = (ks * 4 + (lane >> 4)) ^ (r & 7);
        bfr[ni] = *(const bf16x8*)&lB[r * 64 + p * 8];
      }
#pragma unroll
      for (int mi = 0; mi < 2; ++mi)
#pragma unroll
        for (int ni = 0; ni < 2; ++ni)
          acc[mi][ni] = __builtin_amdgcn_mfma_f32_16x16x32_bf16(af[mi], bfr[ni], acc[mi][ni], 0, 0, 0);
    }
    __syncthreads();
  }

#pragma unroll
  for (int mi = 0; mi < 2; ++mi) {
    int r0 = rowA + wm * 32 + mi * 16 + ((lane >> 4) << 2);
#pragma unroll
    for (int ni = 0; ni < 2; ++ni) {
      int c = rowB + wn * 32 + ni * 16 + (lane & 15);
#pragma unroll
      for (int j = 0; j < 4; ++j)
        Pj[(size_t)(r0 + j) * DIM + c] = __float2bfloat16(acc[mi][ni][j]);
    }
  }
}

// ---- align GEMM + fused tanh/mask/max epilogue.
// Dual-b 128x128 tile, 4 waves, BK=32, TRIPLE-buffered (72 KiB, 2 blk/CU),
// DEPTH-2 prefetch: STAGE(t+2) issued at top of compute(t); end-of-tile sync is
// raw s_barrier + COUNTED vmcnt(6) (tile t+1's 6 loads drained, t+2's stay in
// flight) -- cover = 2 compute phases, vs depth-1's 1 (R6: latency-bound).
// Swizzle (verified 0-conflict in R6): phys slot p holds logical p^((r>>1)&3).
__global__ __launch_bounds__(256, 2) void k_align(const __hip_bfloat16* __restrict__ Pj,
                                                  const __hip_bfloat16* __restrict__ Bt,
                                                  const float* __restrict__ msk,
                                                  unsigned* __restrict__ maxS,
                                                  unsigned* __restrict__ maxT) {
  __shared__ __align__(16) __hip_bfloat16 lA[3 * 128 * 32];
  __shared__ __align__(16) __hip_bfloat16 lB0[3 * 128 * 32];
  __shared__ __align__(16) __hip_bfloat16 lB1[3 * 128 * 32];
  const int tid = threadIdx.x;
  const int lane = tid & 63;
  const int wid = tid >> 6;
  const int wm = wid >> 1, wn = wid & 1;
  const int hi = lane >> 4;

  // decode: xcd owns a in {xcd, xcd+8}; b-pair SLOWEST (concurrent ~64 slots
  // per XCD share one Bt pair -> 2MB L2 working set instead of 8MB).
  const int bid = blockIdx.x;
  const int xcd = bid & 7;
  const int slot = bid >> 3;             // [0,256)
  const int bp = slot >> 5;              // [0,8) slowest
  const int r2 = slot & 31;
  const int a = xcd + 8 * (r2 >> 4);
  const int x = r2 & 15;
  const int bm = x & 3, bn = x >> 2;
  const int b0 = bp * 2, b1 = b0 + 1;

  const int rowA0 = bm * 128, rowB0 = bn * 128;
  const __hip_bfloat16* XA = Pj + (size_t)a * DIM * DIM + (size_t)rowA0 * DIM;
  const __hip_bfloat16* Y0 = Bt + (size_t)b0 * DIM * DIM + (size_t)rowB0 * DIM;
  const __hip_bfloat16* Y1 = Bt + (size_t)b1 * DIM * DIM + (size_t)rowB0 * DIM;

  int goff[2], loff[2];
#pragma unroll
  for (int i = 0; i < 2; ++i) {
    int d16 = i * 256 + tid;
    int r = d16 >> 2, p = d16 & 3;
    goff[i] = r * DIM + ((p ^ ((r >> 1) & 3)) * 8);
    loff[i] = d16 * 8;
  }

  int fA[4], fB[4];
#pragma unroll
  for (int mi = 0; mi < 4; ++mi) {
    int r = wm * 64 + mi * 16 + (lane & 15);
    fA[mi] = r * 32 + ((hi ^ ((r >> 1) & 3)) * 8);
  }
#pragma unroll
  for (int ni = 0; ni < 4; ++ni) {
    int r = wn * 64 + ni * 16 + (lane & 15);
    fB[ni] = r * 32 + ((hi ^ ((r >> 1) & 3)) * 8);
  }

  f32x4 acc0[4][4], acc1[4][4];
#pragma unroll
  for (int mi = 0; mi < 4; ++mi)
#pragma unroll
    for (int ni = 0; ni < 4; ++ni) {
      acc0[mi][ni] = (f32x4){0.f, 0.f, 0.f, 0.f};
      acc1[mi][ni] = (f32x4){0.f, 0.f, 0.f, 0.f};
    }

#define STAGE(kt, c)                                                         \
  {                                                                          \
    _Pragma("unroll") for (int i = 0; i < 2; ++i) {                          \
      gload_lds16(XA + goff[i] + (kt)*32, &lA[(c)*4096 + loff[i]]);          \
      gload_lds16(Y0 + goff[i] + (kt)*32, &lB0[(c)*4096 + loff[i]]);         \
      gload_lds16(Y1 + goff[i] + (kt)*32, &lB1[(c)*4096 + loff[i]]);         \
    }                                                                        \
  }

  // prologue: tiles 0,1 in flight; drain tile 0 (leave tile 1's 6 outstanding)
  STAGE(0, 0);
  STAGE(1, 1);
  asm volatile("s_waitcnt vmcnt(6)" ::: "memory");
  __builtin_amdgcn_sched_barrier(0);
  __builtin_amdgcn_s_barrier();
  __builtin_amdgcn_sched_barrier(0);

#pragma unroll
  for (int t = 0; t < 16; ++t) {
    const int c = t % 3;
    if (t + 2 < 16) STAGE(t + 2, (t + 2) % 3);  // buf freed by compute(t-1)
    bf16x8 af[4], bv0[4], bv1[4];
#pragma unroll
    for (int mi = 0; mi < 4; ++mi) af[mi] = *(const bf16x8*)&lA[c * 4096 + fA[mi]];
#pragma unroll
    for (int ni = 0; ni < 4; ++ni) {
      bv0[ni] = *(const bf16x8*)&lB0[c * 4096 + fB[ni]];
      bv1[ni] = *(const bf16x8*)&lB1[c * 4096 + fB[ni]];
    }
    __builtin_amdgcn_s_setprio(1);
#pragma unroll
    for (int mi = 0; mi < 4; ++mi)
#pragma unroll
      for (int ni = 0; ni < 4; ++ni) {
        acc0[mi][ni] = __builtin_amdgcn_mfma_f32_16x16x32_bf16(af[mi], bv0[ni], acc0[mi][ni], 0, 0, 0);
        acc1[mi][ni] = __builtin_amdgcn_mfma_f32_16x16x32_bf16(af[mi], bv1[ni], acc1[mi][ni], 0, 0, 0);
      }
    __builtin_amdgcn_s_setprio(0);
    if (t < 15) {
      if (t <= 13)
        asm volatile("s_waitcnt vmcnt(6)" ::: "memory");  // drain t+1, keep t+2
      else
        asm volatile("s_waitcnt vmcnt(0)" ::: "memory");  // t=14: only t+1 left
      __builtin_amdgcn_sched_barrier(0);
      __builtin_amdgcn_s_barrier();
      __builtin_amdgcn_sched_barrier(0);
    }
  }
#undef STAGE

  // ---- epilogue: tanh + mask (loaded once, reused for both b) + row/col max
  const float* mk = msk + (size_t)a * DIM * DIM;
  float rmx0[4][4], rmx1[4][4], cmx0[4], cmx1[4];
#pragma unroll
  for (int mi = 0; mi < 4; ++mi)
#pragma unroll
    for (int j = 0; j < 4; ++j) { rmx0[mi][j] = -INFINITY; rmx1[mi][j] = -INFINITY; }
#pragma unroll
  for (int ni = 0; ni < 4; ++ni) { cmx0[ni] = -INFINITY; cmx1[ni] = -INFINITY; }

#pragma unroll
  for (int mi = 0; mi < 4; ++mi) {
    int s0 = rowA0 + wm * 64 + mi * 16 + hi * 4;
#pragma unroll
    for (int ni = 0; ni < 4; ++ni) {
      int t = rowB0 + wn * 64 + ni * 16 + (lane & 15);
#pragma unroll
      for (int j = 0; j < 4; ++j) {
        float m = mk[(size_t)(s0 + j) * DIM + t];
        float v0 = tanh_fast(acc0[mi][ni][j]) + m;
        float v1 = tanh_fast(acc1[mi][ni][j]) + m;
        rmx0[mi][j] = fmaxf(rmx0[mi][j], v0);
        rmx1[mi][j] = fmaxf(rmx1[mi][j], v1);
        cmx0[ni] = fmaxf(cmx0[ni], v0);
        cmx1[ni] = fmaxf(cmx1[ni], v1);
      }
    }
  }

  const int pr0 = a * 16 + b0, pr1 = a * 16 + b1;
#pragma unroll
  for (int mi = 0; mi < 4; ++mi)
#pragma unroll
    for (int j = 0; j < 4; ++j) {
      float r0 = rmx0[mi][j], r1 = rmx1[mi][j];
      r0 = fmaxf(r0, __shfl_xor(r0, 1));
      r0 = fmaxf(r0, __shfl_xor(r0, 2));
      r0 = fmaxf(r0, __shfl_xor(r0, 4));
      r0 = fmaxf(r0, __shfl_xor(r0, 8));
      r1 = fmaxf(r1, __shfl_xor(r1, 1));
      r1 = fmaxf(r1, __shfl_xor(r1, 2));
      r1 = fmaxf(r1, __shfl_xor(r1, 4));
      r1 = fmaxf(r1, __shfl_xor(r1, 8));
      if ((lane & 15) == 0) {
        int s = rowA0 + wm * 64 + mi * 16 + hi * 4 + j;
        atomicMax(&maxS[(size_t)pr0 * DIM + s], fenc(r0));
        atomicMax(&maxS[(size_t)pr1 * DIM + s], fenc(r1));
      }
    }
#pragma unroll
  for (int ni = 0; ni < 4; ++ni) {
    float c0 = cmx0[ni], c1 = cmx1[ni];
    c0 = fmaxf(c0, __shfl_xor(c0, 16));
    c0 = fmaxf(c0, __shfl_xor(c0, 32));
    c1 = fmaxf(c1, __shfl_xor(c1, 16));
    c1 = fmaxf(c1, __shfl_xor(c1, 32));
    if (lane < 16) {
      int t = rowB0 + wn * 64 + ni * 16 + lane;
      atomicMax(&maxT[(size_t)pr0 * DIM + t], fenc(c0));
      atomicMax(&maxT[(size_t)pr1 * DIM + t], fenc(c1));
    }
  }
}

// ---- softmax over the 512 max-logits of each (pair, side) ----
__global__ __launch_bounds__(64) void k_softmax(const unsigned* __restrict__ menc,
                                                float* __restrict__ sc) {
  int pair = blockIdx.x, side = blockIdx.y;
  const unsigned* buf = menc + (size_t)side * 256 * DIM + (size_t)pair * DIM;
  float* out = sc + (size_t)side * 256 * DIM + (size_t)pair * DIM;
  int lane = threadIdx.x;
  float v[8];
  float m = -INFINITY;
#pragma unroll
  for (int k = 0; k < 8; ++k) {
    v[k] = fdec(buf[lane + 64 * k]);
    m = fmaxf(m, v[k]);
  }
#pragma unroll
  for (int off = 1; off < 64; off <<= 1) m = fmaxf(m, __shfl_xor(m, off));
  float s = 0.f;
#pragma unroll
  for (int k = 0; k < 8; ++k) {
    v[k] = expf(v[k] - m);
    s += v[k];
  }
#pragma unroll
  for (int off = 1; off < 64; off <<= 1) s += __shfl_xor(s, off);
  float inv = 1.0f / s;
#pragma unroll
  for (int k = 0; k < 8; ++k) out[lane + 64 * k] = v[k] * inv;
}

// ---- attention-weighted pooling: out[pair][d] = sum_s mat[d][s] * score[pair][s]
__global__ __launch_bounds__(256) void k_pool(const float* __restrict__ A,
                                              const float* __restrict__ B,
                                              const float* __restrict__ sc,
                                              float* __restrict__ out) {
  __shared__ float ta[128][65];
  __shared__ float ts[16][128];
  int t = threadIdx.x;
  int d0 = blockIdx.x * 64;
  int y = blockIdx.y, side = blockIdx.z;
  const float* mat = (side ? B : A) + (size_t)y * DIM * DIM;
  const float* scb = sc + (size_t)side * 256 * DIM;
  float* ob = out + (size_t)side * 256 * DIM;
  int dl = t & 63, g = t >> 6;
  float acc[4] = {0.f, 0.f, 0.f, 0.f};
  for (int st = 0; st < 4; ++st) {
    __syncthreads();
#pragma unroll
    for (int i = 0; i < 32; ++i) {
      int idx = t + 256 * i;
      int r = idx >> 7, c = idx & 127;
      ta[c][r] = mat[(size_t)(d0 + r) * DIM + st * 128 + c];
    }
#pragma unroll
    for (int i = 0; i < 8; ++i) {
      int idx = t + 256 * i;
      int p = idx >> 7, s = idx & 127;
      int pair = side ? (p * 16 + y) : (y * 16 + p);
      ts[p][s] = scb[(size_t)pair * DIM + st * 128 + s];
    }
    __syncthreads();
    for (int s = 0; s < 128; ++s) {
      float v = ta[s][dl];
#pragma unroll
      for (int i = 0; i < 4; ++i) acc[i] += v * ts[g * 4 + i][s];
    }
  }
#pragma unroll
  for (int i = 0; i < 4; ++i) {
    int p = g * 4 + i;
    int pair = side ? (p * 16 + y) : (y * 16 + p);
    ob[(size_t)pair * DIM + d0 + dl] = acc[i];
  }
}

extern "C" void kernel_launch(void* const* d_in, const int* in_sizes, int n_in,
                              void* d_out, int out_size, void* d_ws, size_t ws_size,
                              hipStream_t stream) {
  (void)in_sizes; (void)n_in; (void)out_size; (void)ws_size;
  const float* A = (const float*)d_in[0];    // (16, 512, 512) d-major
  const float* B = (const float*)d_in[1];    // (16, 512, 512) d-major
  const float* msk = (const float*)d_in[2];  // (16, 512, 512)
  const float* U = (const float*)d_in[3];    // (512, 512)

  char* w = (char*)d_ws;
  __hip_bfloat16* At = (__hip_bfloat16*)(w + 0);         //  8 MB: [a][s][d] == [8192][512]
  __hip_bfloat16* Bt = (__hip_bfloat16*)(w + 8388608);   //  8 MB: [b][t][e]
  __hip_bfloat16* Ut = (__hip_bfloat16*)(w + 16777216);  //  512 KB: [e][d]
  __hip_bfloat16* Pj = (__hip_bfloat16*)(w + 17301504);  //  8 MB: [a][s][e] == [8192][512]
  unsigned* menc = (unsigned*)(w + 25690112);            //  1 MB: maxS | maxT
  float* sc = (float*)(w + 26738688);                    //  1 MB: scores
  unsigned* maxS = menc;
  unsigned* maxT = menc + 256 * DIM;

  k_prep<<<dim3(16, 16, 34), dim3(32, 8), 0, stream>>>(A, B, U, At, Bt, Ut, menc);
  k_proj64<<<dim3(128, 8), 256, 0, stream>>>(At, Ut, Pj);
  k_align<<<2048, 256, 0, stream>>>(Pj, Bt, msk, maxS, maxT);
  k_softmax<<<dim3(256, 2), 64, 0, stream>>>(menc, sc);
  k_pool<<<dim3(8, 16, 2), 256, 0, stream>>>(A, B, sc, (float*)d_out);
}

// Round 8
// 143.513 us; speedup vs baseline: 1.4083x; 1.3493x over previous
//
#include <hip/hip_runtime.h>
#include <hip/hip_bf16.h>
#include <stdint.h>

#define DIM 512

typedef __bf16 bf16x8 __attribute__((ext_vector_type(8)));
typedef float f32x4 __attribute__((ext_vector_type(4)));

// ---- monotonic float<->uint encoding for atomicMax on signed floats ----
__device__ __forceinline__ unsigned fenc(float f) {
  unsigned u = __float_as_uint(f);
  return (u & 0x80000000u) ? ~u : (u | 0x80000000u);
}
__device__ __forceinline__ float fdec(unsigned e) {
  unsigned u = (e & 0x80000000u) ? (e & 0x7FFFFFFFu) : ~e;
  return __uint_as_float(u);
}

// ---- fast tanh: 1 - 2/(exp(2x)+1). ~5 VALU ops, exact at saturated tails.
__device__ __forceinline__ float tanh_fast(float x) {
  float e = __expf(2.0f * x);
  return 1.0f - 2.0f * __builtin_amdgcn_rcpf(e + 1.0f);
}

// ---- prep: z<32 transpose A/B +convert; z==32 transpose U; z==33 init max ----
__global__ __launch_bounds__(256) void k_prep(const float* __restrict__ A,
                                              const float* __restrict__ B,
                                              const float* __restrict__ U,
                                              __hip_bfloat16* __restrict__ At,
                                              __hip_bfloat16* __restrict__ Bt,
                                              __hip_bfloat16* __restrict__ Ut,
                                              unsigned* __restrict__ menc) {
  int z = blockIdx.z;
  int tx = threadIdx.x, ty = threadIdx.y;
  if (z == 33) {
    int gid = (blockIdx.y * 16 + blockIdx.x) * 256 + ty * 32 + tx;
#pragma unroll
    for (int k = 0; k < 4; ++k) menc[gid + 65536 * k] = 0x007FFFFFu;  // enc(-inf)
    return;
  }
  __shared__ float tile[32][33];
  int x0 = blockIdx.x * 32, y0 = blockIdx.y * 32;
  const float* src;
  __hip_bfloat16* dst;
  if (z == 32) {
    src = U;
    dst = Ut;
  } else if (z < 16) {
    src = A + (size_t)z * DIM * DIM;
    dst = At + (size_t)z * DIM * DIM;
  } else {
    src = B + (size_t)(z - 16) * DIM * DIM;
    dst = Bt + (size_t)(z - 16) * DIM * DIM;
  }
#pragma unroll
  for (int k = 0; k < 4; ++k)
    tile[ty + 8 * k][tx] = src[(size_t)(y0 + ty + 8 * k) * DIM + x0 + tx];
  __syncthreads();
#pragma unroll
  for (int k = 0; k < 4; ++k)
    dst[(size_t)(x0 + ty + 8 * k) * DIM + y0 + tx] = __float2bfloat16(tile[tx][ty + 8 * k]);
}

// ---- async global->LDS, 16B per lane ----
__device__ __forceinline__ void gload_lds16(const __hip_bfloat16* g, __hip_bfloat16* l) {
  __builtin_amdgcn_global_load_lds(
      (const __attribute__((address_space(1))) uint32_t*)g,
      (__attribute__((address_space(3))) uint32_t*)l, 16, 0, 0);
}

// ---- proj GEMM, M flattened to 8192: Pj[8192][512] = At[8192][512] @ Ut[512][512]^T
__global__ __launch_bounds__(256, 4) void k_proj64(const __hip_bfloat16* __restrict__ At,
                                                   const __hip_bfloat16* __restrict__ Ut,
                                                   __hip_bfloat16* __restrict__ Pj) {
  __shared__ __align__(16) __hip_bfloat16 lA[64 * 64];
  __shared__ __align__(16) __hip_bfloat16 lB[64 * 64];
  const int tid = threadIdx.x, lane = tid & 63, wid = tid >> 6;
  const int wm = wid >> 1, wn = wid & 1;
  const int rowA = blockIdx.x * 64, rowB = blockIdx.y * 64;

  int sl16[2], srow[2], scol[2];
#pragma unroll
  for (int i = 0; i < 2; ++i) {
    int d16 = i * 256 + tid;
    int r = d16 >> 3, p = d16 & 7;
    sl16[i] = d16;
    srow[i] = r;
    scol[i] = (p ^ (r & 7)) * 8;
  }

  f32x4 acc[2][2];
#pragma unroll
  for (int mi = 0; mi < 2; ++mi)
#pragma unroll
    for (int ni = 0; ni < 2; ++ni) acc[mi][ni] = (f32x4){0.f, 0.f, 0.f, 0.f};

  for (int k0 = 0; k0 < DIM; k0 += 64) {
#pragma unroll
    for (int i = 0; i < 2; ++i) {
      gload_lds16(At + (size_t)(rowA + srow[i]) * DIM + k0 + scol[i], &lA[sl16[i] * 8]);
      gload_lds16(Ut + (size_t)(rowB + srow[i]) * DIM + k0 + scol[i], &lB[sl16[i] * 8]);
    }
    __syncthreads();
#pragma unroll
    for (int ks = 0; ks < 2; ++ks) {
      bf16x8 af[2], bfr[2];
#pragma unroll
      for (int mi = 0; mi < 2; ++mi) {
        int r = wm * 32 + mi * 16 + (lane & 15);
        int p = (ks * 4 + (lane >> 4)) ^ (r & 7);
        af[mi] = *(const bf16x8*)&lA[r * 64 + p * 8];
      }
#pragma unroll
      for (int ni = 0; ni < 2; ++ni) {
        int r = wn * 32 + ni * 16 + (lane & 15);
        int p = (ks * 4 + (lane >> 4)) ^ (r & 7);
        bfr[ni] = *(const bf16x8*)&lB[r * 64 + p * 8];
      }
#pragma unroll
      for (int mi = 0; mi < 2; ++mi)
#pragma unroll
        for (int ni = 0; ni < 2; ++ni)
          acc[mi][ni] = __builtin_amdgcn_mfma_f32_16x16x32_bf16(af[mi], bfr[ni], acc[mi][ni], 0, 0, 0);
    }
    __syncthreads();
  }

#pragma unroll
  for (int mi = 0; mi < 2; ++mi) {
    int r0 = rowA + wm * 32 + mi * 16 + ((lane >> 4) << 2);
#pragma unroll
    for (int ni = 0; ni < 2; ++ni) {
      int c = rowB + wn * 32 + ni * 16 + (lane & 15);
#pragma unroll
      for (int j = 0; j < 4; ++j)
        Pj[(size_t)(r0 + j) * DIM + c] = __float2bfloat16(acc[mi][ni][j]);
    }
  }
}

// ---- align GEMM + fused tanh/mask/max epilogue.
// R3 structure EXACT (best measured: 99.5us, MfmaUtil 30%): dual-b 128x128,
// 4 waves, BK=64, single-buffered, 2 barriers per K-tile, 64 MFMA/wave/phase.
// Only change vs R3: bp-slowest bijective decode (R7-verified, FETCH 88->72MB).
__global__ __launch_bounds__(256, 2) void k_align(const __hip_bfloat16* __restrict__ Pj,
                                                  const __hip_bfloat16* __restrict__ Bt,
                                                  const float* __restrict__ msk,
                                                  unsigned* __restrict__ maxS,
                                                  unsigned* __restrict__ maxT) {
  __shared__ __align__(16) __hip_bfloat16 lA[128 * 64];
  __shared__ __align__(16) __hip_bfloat16 lB0[128 * 64];
  __shared__ __align__(16) __hip_bfloat16 lB1[128 * 64];
  const int tid = threadIdx.x;
  const int lane = tid & 63;
  const int wid = tid >> 6;
  const int wm = wid >> 1, wn = wid & 1;

  // decode: xcd owns a in {xcd, xcd+8}; b-pair slowest -> per-XCD concurrent
  // working set = one Bt pair (1MB) + 2 a's of Pj/mask (L2-resident).
  const int bid = blockIdx.x;
  const int xcd = bid & 7;
  const int slot = bid >> 3;             // [0,256)
  const int bp = slot >> 5;              // [0,8) slowest
  const int r2 = slot & 31;
  const int a = xcd + 8 * (r2 >> 4);
  const int x = r2 & 15;
  const int bm = x & 3, bn = x >> 2;
  const int b0 = bp * 2, b1 = b0 + 1;

  const __hip_bfloat16* X = Pj + (size_t)a * DIM * DIM;
  const __hip_bfloat16* Y0 = Bt + (size_t)b0 * DIM * DIM;
  const __hip_bfloat16* Y1 = Bt + (size_t)b1 * DIM * DIM;

  // staging: thread t covers 16B slots {t, t+256, t+512, t+768}; LDS dest
  // linear (HW requirement), global col pre-XOR-swizzled (involution p^(r&7)).
  int sl16[4], srow[4], scol[4];
#pragma unroll
  for (int i = 0; i < 4; ++i) {
    int d16 = i * 256 + tid;
    int r = d16 >> 3, p = d16 & 7;
    sl16[i] = d16;
    srow[i] = r;
    scol[i] = (p ^ (r & 7)) * 8;
  }

  f32x4 acc0[4][4], acc1[4][4];
#pragma unroll
  for (int mi = 0; mi < 4; ++mi)
#pragma unroll
    for (int ni = 0; ni < 4; ++ni) {
      acc0[mi][ni] = (f32x4){0.f, 0.f, 0.f, 0.f};
      acc1[mi][ni] = (f32x4){0.f, 0.f, 0.f, 0.f};
    }

  const int rowA = bm * 128, rowB = bn * 128;
  for (int k0 = 0; k0 < DIM; k0 += 64) {
#pragma unroll
    for (int i = 0; i < 4; ++i) {
      gload_lds16(X + (size_t)(rowA + srow[i]) * DIM + k0 + scol[i], &lA[sl16[i] * 8]);
      gload_lds16(Y0 + (size_t)(rowB + srow[i]) * DIM + k0 + scol[i], &lB0[sl16[i] * 8]);
      gload_lds16(Y1 + (size_t)(rowB + srow[i]) * DIM + k0 + scol[i], &lB1[sl16[i] * 8]);
    }
    __syncthreads();
#pragma unroll
    for (int ks = 0; ks < 2; ++ks) {
      bf16x8 af[4], b0f[4], b1f[4];
#pragma unroll
      for (int mi = 0; mi < 4; ++mi) {
        int r = wm * 64 + mi * 16 + (lane & 15);
        int p = (ks * 4 + (lane >> 4)) ^ (r & 7);
        af[mi] = *(const bf16x8*)&lA[r * 64 + p * 8];
      }
#pragma unroll
      for (int ni = 0; ni < 4; ++ni) {
        int r = wn * 64 + ni * 16 + (lane & 15);
        int p = (ks * 4 + (lane >> 4)) ^ (r & 7);
        b0f[ni] = *(const bf16x8*)&lB0[r * 64 + p * 8];
        b1f[ni] = *(const bf16x8*)&lB1[r * 64 + p * 8];
      }
#pragma unroll
      for (int mi = 0; mi < 4; ++mi)
#pragma unroll
        for (int ni = 0; ni < 4; ++ni) {
          acc0[mi][ni] = __builtin_amdgcn_mfma_f32_16x16x32_bf16(af[mi], b0f[ni], acc0[mi][ni], 0, 0, 0);
          acc1[mi][ni] = __builtin_amdgcn_mfma_f32_16x16x32_bf16(af[mi], b1f[ni], acc1[mi][ni], 0, 0, 0);
        }
    }
    __syncthreads();
  }

  // ---- epilogue: tanh + mask (loaded once, reused for both b) + row/col max
  const float* mk = msk + (size_t)a * DIM * DIM;
  float rmx0[4][4], rmx1[4][4], cmx0[4], cmx1[4];
#pragma unroll
  for (int mi = 0; mi < 4; ++mi)
#pragma unroll
    for (int j = 0; j < 4; ++j) { rmx0[mi][j] = -INFINITY; rmx1[mi][j] = -INFINITY; }
#pragma unroll
  for (int ni = 0; ni < 4; ++ni) { cmx0[ni] = -INFINITY; cmx1[ni] = -INFINITY; }

#pragma unroll
  for (int mi = 0; mi < 4; ++mi) {
    int s0 = rowA + wm * 64 + mi * 16 + ((lane >> 4) << 2);
#pragma unroll
    for (int ni = 0; ni < 4; ++ni) {
      int t = rowB + wn * 64 + ni * 16 + (lane & 15);
#pragma unroll
      for (int j = 0; j < 4; ++j) {
        float m = mk[(size_t)(s0 + j) * DIM + t];
        float v0 = tanh_fast(acc0[mi][ni][j]) + m;
        float v1 = tanh_fast(acc1[mi][ni][j]) + m;
        rmx0[mi][j] = fmaxf(rmx0[mi][j], v0);
        rmx1[mi][j] = fmaxf(rmx1[mi][j], v1);
        cmx0[ni] = fmaxf(cmx0[ni], v0);
        cmx1[ni] = fmaxf(cmx1[ni], v1);
      }
    }
  }

  const int pr0 = a * 16 + b0, pr1 = a * 16 + b1;
#pragma unroll
  for (int mi = 0; mi < 4; ++mi)
#pragma unroll
    for (int j = 0; j < 4; ++j) {
      float r0 = rmx0[mi][j], r1 = rmx1[mi][j];
      r0 = fmaxf(r0, __shfl_xor(r0, 1));
      r0 = fmaxf(r0, __shfl_xor(r0, 2));
      r0 = fmaxf(r0, __shfl_xor(r0, 4));
      r0 = fmaxf(r0, __shfl_xor(r0, 8));
      r1 = fmaxf(r1, __shfl_xor(r1, 1));
      r1 = fmaxf(r1, __shfl_xor(r1, 2));
      r1 = fmaxf(r1, __shfl_xor(r1, 4));
      r1 = fmaxf(r1, __shfl_xor(r1, 8));
      if ((lane & 15) == 0) {
        int s = rowA + wm * 64 + mi * 16 + ((lane >> 4) << 2) + j;
        atomicMax(&maxS[(size_t)pr0 * DIM + s], fenc(r0));
        atomicMax(&maxS[(size_t)pr1 * DIM + s], fenc(r1));
      }
    }
#pragma unroll
  for (int ni = 0; ni < 4; ++ni) {
    float c0 = cmx0[ni], c1 = cmx1[ni];
    c0 = fmaxf(c0, __shfl_xor(c0, 16));
    c0 = fmaxf(c0, __shfl_xor(c0, 32));
    c1 = fmaxf(c1, __shfl_xor(c1, 16));
    c1 = fmaxf(c1, __shfl_xor(c1, 32));
    if (lane < 16) {
      int t = rowB + wn * 64 + ni * 16 + lane;
      atomicMax(&maxT[(size_t)pr0 * DIM + t], fenc(c0));
      atomicMax(&maxT[(size_t)pr1 * DIM + t], fenc(c1));
    }
  }
}

// ---- softmax over the 512 max-logits of each (pair, side) ----
__global__ __launch_bounds__(64) void k_softmax(const unsigned* __restrict__ menc,
                                                float* __restrict__ sc) {
  int pair = blockIdx.x, side = blockIdx.y;
  const unsigned* buf = menc + (size_t)side * 256 * DIM + (size_t)pair * DIM;
  float* out = sc + (size_t)side * 256 * DIM + (size_t)pair * DIM;
  int lane = threadIdx.x;
  float v[8];
  float m = -INFINITY;
#pragma unroll
  for (int k = 0; k < 8; ++k) {
    v[k] = fdec(buf[lane + 64 * k]);
    m = fmaxf(m, v[k]);
  }
#pragma unroll
  for (int off = 1; off < 64; off <<= 1) m = fmaxf(m, __shfl_xor(m, off));
  float s = 0.f;
#pragma unroll
  for (int k = 0; k < 8; ++k) {
    v[k] = expf(v[k] - m);
    s += v[k];
  }
#pragma unroll
  for (int off = 1; off < 64; off <<= 1) s += __shfl_xor(s, off);
  float inv = 1.0f / s;
#pragma unroll
  for (int k = 0; k < 8; ++k) out[lane + 64 * k] = v[k] * inv;
}

// ---- attention-weighted pooling: out[pair][d] = sum_s mat[d][s] * score[pair][s]
// float4-vectorized staging (G13).
__global__ __launch_bounds__(256) void k_pool(const float* __restrict__ A,
                                              const float* __restrict__ B,
                                              const float* __restrict__ sc,
                                              float* __restrict__ out) {
  __shared__ float ta[128][65];
  __shared__ float ts[16][128];
  int t = threadIdx.x;
  int d0 = blockIdx.x * 64;
  int y = blockIdx.y, side = blockIdx.z;
  const float* mat = (side ? B : A) + (size_t)y * DIM * DIM;
  const float* scb = sc + (size_t)side * 256 * DIM;
  float* ob = out + (size_t)side * 256 * DIM;
  int dl = t & 63, g = t >> 6;
  float acc[4] = {0.f, 0.f, 0.f, 0.f};
  for (int st = 0; st < 4; ++st) {
    __syncthreads();
    // stage 64 d-rows x 128 s-cols, transposed into ta[s][d], float4 loads
#pragma unroll
    for (int i = 0; i < 8; ++i) {
      int idx = t + 256 * i;          // [0,2048): 64 r x 32 c4
      int r = idx >> 5, c4 = idx & 31;
      float4 v = *(const float4*)&mat[(size_t)(d0 + r) * DIM + st * 128 + c4 * 4];
      ta[c4 * 4 + 0][r] = v.x;
      ta[c4 * 4 + 1][r] = v.y;
      ta[c4 * 4 + 2][r] = v.z;
      ta[c4 * 4 + 3][r] = v.w;
    }
    // stage 16 partners x 128 scores, float4 loads
#pragma unroll
    for (int i = 0; i < 2; ++i) {
      int idx = t + 256 * i;          // [0,512): 16 p x 32 c4
      int p = idx >> 5, c4 = idx & 31;
      int pair = side ? (p * 16 + y) : (y * 16 + p);
      float4 v = *(const float4*)&scb[(size_t)pair * DIM + st * 128 + c4 * 4];
      ts[p][c4 * 4 + 0] = v.x;
      ts[p][c4 * 4 + 1] = v.y;
      ts[p][c4 * 4 + 2] = v.z;
      ts[p][c4 * 4 + 3] = v.w;
    }
    __syncthreads();
    for (int s = 0; s < 128; ++s) {
      float v = ta[s][dl];
#pragma unroll
      for (int i = 0; i < 4; ++i) acc[i] += v * ts[g * 4 + i][s];
    }
  }
#pragma unroll
  for (int i = 0; i < 4; ++i) {
    int p = g * 4 + i;
    int pair = side ? (p * 16 + y) : (y * 16 + p);
    ob[(size_t)pair * DIM + d0 + dl] = acc[i];
  }
}

extern "C" void kernel_launch(void* const* d_in, const int* in_sizes, int n_in,
                              void* d_out, int out_size, void* d_ws, size_t ws_size,
                              hipStream_t stream) {
  (void)in_sizes; (void)n_in; (void)out_size; (void)ws_size;
  const float* A = (const float*)d_in[0];    // (16, 512, 512) d-major
  const float* B = (const float*)d_in[1];    // (16, 512, 512) d-major
  const float* msk = (const float*)d_in[2];  // (16, 512, 512)
  const float* U = (const float*)d_in[3];    // (512, 512)

  char* w = (char*)d_ws;
  __hip_bfloat16* At = (__hip_bfloat16*)(w + 0);         //  8 MB: [a][s][d] == [8192][512]
  __hip_bfloat16* Bt = (__hip_bfloat16*)(w + 8388608);   //  8 MB: [b][t][e]
  __hip_bfloat16* Ut = (__hip_bfloat16*)(w + 16777216);  //  512 KB: [e][d]
  __hip_bfloat16* Pj = (__hip_bfloat16*)(w + 17301504);  //  8 MB: [a][s][e] == [8192][512]
  unsigned* menc = (unsigned*)(w + 25690112);            //  1 MB: maxS | maxT
  float* sc = (float*)(w + 26738688);                    //  1 MB: scores
  unsigned* maxS = menc;
  unsigned* maxT = menc + 256 * DIM;

  k_prep<<<dim3(16, 16, 34), dim3(32, 8), 0, stream>>>(A, B, U, At, Bt, Ut, menc);
  k_proj64<<<dim3(128, 8), 256, 0, stream>>>(At, Ut, Pj);
  k_align<<<2048, 256, 0, stream>>>(Pj, Bt, msk, maxS, maxT);
  k_softmax<<<dim3(256, 2), 64, 0, stream>>>(menc, sc);
  k_pool<<<dim3(8, 16, 2), 256, 0, stream>>>(A, B, sc, (float*)d_out);
}

// Round 9
// 133.798 us; speedup vs baseline: 1.5106x; 1.0726x over previous
//
#include <hip/hip_runtime.h>
#include <hip/hip_bf16.h>
#include <stdint.h>

#define DIM 512

typedef __bf16 bf16x8 __attribute__((ext_vector_type(8)));
typedef float f32x4 __attribute__((ext_vector_type(4)));

// ---- monotonic float<->uint encoding for atomicMax on signed floats ----
__device__ __forceinline__ unsigned fenc(float f) {
  unsigned u = __float_as_uint(f);
  return (u & 0x80000000u) ? ~u : (u | 0x80000000u);
}
__device__ __forceinline__ float fdec(unsigned e) {
  unsigned u = (e & 0x80000000u) ? (e & 0x7FFFFFFFu) : ~e;
  return __uint_as_float(u);
}

// ---- fast tanh: 1 - 2/(exp(2x)+1). ~5 VALU ops, exact at saturated tails.
__device__ __forceinline__ float tanh_fast(float x) {
  float e = __expf(2.0f * x);
  return 1.0f - 2.0f * __builtin_amdgcn_rcpf(e + 1.0f);
}

// ---- prep: z<32 transpose A/B +convert; z==32 transpose U; z==33 init max ----
__global__ __launch_bounds__(256) void k_prep(const float* __restrict__ A,
                                              const float* __restrict__ B,
                                              const float* __restrict__ U,
                                              __hip_bfloat16* __restrict__ At,
                                              __hip_bfloat16* __restrict__ Bt,
                                              __hip_bfloat16* __restrict__ Ut,
                                              unsigned* __restrict__ menc) {
  int z = blockIdx.z;
  int tx = threadIdx.x, ty = threadIdx.y;
  if (z == 33) {
    int gid = (blockIdx.y * 16 + blockIdx.x) * 256 + ty * 32 + tx;
#pragma unroll
    for (int k = 0; k < 4; ++k) menc[gid + 65536 * k] = 0x007FFFFFu;  // enc(-inf)
    return;
  }
  __shared__ float tile[32][33];
  int x0 = blockIdx.x * 32, y0 = blockIdx.y * 32;
  const float* src;
  __hip_bfloat16* dst;
  if (z == 32) {
    src = U;
    dst = Ut;
  } else if (z < 16) {
    src = A + (size_t)z * DIM * DIM;
    dst = At + (size_t)z * DIM * DIM;
  } else {
    src = B + (size_t)(z - 16) * DIM * DIM;
    dst = Bt + (size_t)(z - 16) * DIM * DIM;
  }
#pragma unroll
  for (int k = 0; k < 4; ++k)
    tile[ty + 8 * k][tx] = src[(size_t)(y0 + ty + 8 * k) * DIM + x0 + tx];
  __syncthreads();
#pragma unroll
  for (int k = 0; k < 4; ++k)
    dst[(size_t)(x0 + ty + 8 * k) * DIM + y0 + tx] = __float2bfloat16(tile[tx][ty + 8 * k]);
}

// ---- mask f32 -> bf16 (exact for 0 / +-inf masks). Runs AFTER proj64 and
// writes into At's workspace slot (At is dead by then) to avoid growing d_ws.
__global__ __launch_bounds__(256) void k_mskconv(const float* __restrict__ msk,
                                                 __hip_bfloat16* __restrict__ out) {
  size_t i = ((size_t)blockIdx.x * 256 + threadIdx.x) * 4;
  float4 v = *(const float4*)&msk[i];
  union { __hip_bfloat16 h[4]; short4 s4; } u;
  u.h[0] = __float2bfloat16(v.x);
  u.h[1] = __float2bfloat16(v.y);
  u.h[2] = __float2bfloat16(v.z);
  u.h[3] = __float2bfloat16(v.w);
  *(short4*)&out[i] = u.s4;
}

// ---- async global->LDS, 16B per lane ----
__device__ __forceinline__ void gload_lds16(const __hip_bfloat16* g, __hip_bfloat16* l) {
  __builtin_amdgcn_global_load_lds(
      (const __attribute__((address_space(1))) uint32_t*)g,
      (__attribute__((address_space(3))) uint32_t*)l, 16, 0, 0);
}

// ---- proj GEMM, M flattened to 8192: Pj[8192][512] = At[8192][512] @ Ut[512][512]^T
__global__ __launch_bounds__(256, 4) void k_proj64(const __hip_bfloat16* __restrict__ At,
                                                   const __hip_bfloat16* __restrict__ Ut,
                                                   __hip_bfloat16* __restrict__ Pj) {
  __shared__ __align__(16) __hip_bfloat16 lA[64 * 64];
  __shared__ __align__(16) __hip_bfloat16 lB[64 * 64];
  const int tid = threadIdx.x, lane = tid & 63, wid = tid >> 6;
  const int wm = wid >> 1, wn = wid & 1;
  const int rowA = blockIdx.x * 64, rowB = blockIdx.y * 64;

  int sl16[2], srow[2], scol[2];
#pragma unroll
  for (int i = 0; i < 2; ++i) {
    int d16 = i * 256 + tid;
    int r = d16 >> 3, p = d16 & 7;
    sl16[i] = d16;
    srow[i] = r;
    scol[i] = (p ^ (r & 7)) * 8;
  }

  f32x4 acc[2][2];
#pragma unroll
  for (int mi = 0; mi < 2; ++mi)
#pragma unroll
    for (int ni = 0; ni < 2; ++ni) acc[mi][ni] = (f32x4){0.f, 0.f, 0.f, 0.f};

  for (int k0 = 0; k0 < DIM; k0 += 64) {
#pragma unroll
    for (int i = 0; i < 2; ++i) {
      gload_lds16(At + (size_t)(rowA + srow[i]) * DIM + k0 + scol[i], &lA[sl16[i] * 8]);
      gload_lds16(Ut + (size_t)(rowB + srow[i]) * DIM + k0 + scol[i], &lB[sl16[i] * 8]);
    }
    __syncthreads();
#pragma unroll
    for (int ks = 0; ks < 2; ++ks) {
      bf16x8 af[2], bfr[2];
#pragma unroll
      for (int mi = 0; mi < 2; ++mi) {
        int r = wm * 32 + mi * 16 + (lane & 15);
        int p = (ks * 4 + (lane >> 4)) ^ (r & 7);
        af[mi] = *(const bf16x8*)&lA[r * 64 + p * 8];
      }
#pragma unroll
      for (int ni = 0; ni < 2; ++ni) {
        int r = wn * 32 + ni * 16 + (lane & 15);
        int p = (ks * 4 + (lane >> 4)) ^ (r & 7);
        bfr[ni] = *(const bf16x8*)&lB[r * 64 + p * 8];
      }
#pragma unroll
      for (int mi = 0; mi < 2; ++mi)
#pragma unroll
        for (int ni = 0; ni < 2; ++ni)
          acc[mi][ni] = __builtin_amdgcn_mfma_f32_16x16x32_bf16(af[mi], bfr[ni], acc[mi][ni], 0, 0, 0);
    }
    __syncthreads();
  }

#pragma unroll
  for (int mi = 0; mi < 2; ++mi) {
    int r0 = rowA + wm * 32 + mi * 16 + ((lane >> 4) << 2);
#pragma unroll
    for (int ni = 0; ni < 2; ++ni) {
      int c = rowB + wn * 32 + ni * 16 + (lane & 15);
#pragma unroll
      for (int j = 0; j < 4; ++j)
        Pj[(size_t)(r0 + j) * DIM + c] = __float2bfloat16(acc[mi][ni][j]);
    }
  }
}

// ---- align GEMM + fused tanh/mask/max epilogue.
// R3 structure + decode EXACT (best measured: 99.5us): dual-b 128x128, 4 waves,
// BK=64, single-buffered, 64 MFMA/wave/phase, one-a-per-window L2 residency.
// Only change: mask read as bf16 (halves the dominant epilogue stream).
__global__ __launch_bounds__(256, 2) void k_align(const __hip_bfloat16* __restrict__ Pj,
                                                  const __hip_bfloat16* __restrict__ Bt,
                                                  const __hip_bfloat16* __restrict__ msk,
                                                  unsigned* __restrict__ maxS,
                                                  unsigned* __restrict__ maxT) {
  __shared__ __align__(16) __hip_bfloat16 lA[128 * 64];
  __shared__ __align__(16) __hip_bfloat16 lB0[128 * 64];
  __shared__ __align__(16) __hip_bfloat16 lB1[128 * 64];
  const int tid = threadIdx.x;
  const int lane = tid & 63;
  const int wid = tid >> 6;
  const int wm = wid >> 1, wn = wid & 1;

  // R3 decode: xcd = bid&7 owns a in {xcd, xcd+8}; a slowest within slot ->
  // concurrent window stays on ONE a (Pj+mask L2-resident).
  const int bid = blockIdx.x;
  const int xcd = bid & 7;
  const int slot = bid >> 3;              // [0,256)
  const int a = xcd + 8 * (slot >> 7);    // 2 a's per xcd
  const int rem = slot & 127;             // [0,128)
  const int bp = rem >> 4;                // [0,8): b-pair
  const int x = rem & 15;
  const int bm = x & 3, bn = x >> 2;
  const int b0 = bp * 2, b1 = b0 + 1;

  const __hip_bfloat16* X = Pj + (size_t)a * DIM * DIM;
  const __hip_bfloat16* Y0 = Bt + (size_t)b0 * DIM * DIM;
  const __hip_bfloat16* Y1 = Bt + (size_t)b1 * DIM * DIM;

  int sl16[4], srow[4], scol[4];
#pragma unroll
  for (int i = 0; i < 4; ++i) {
    int d16 = i * 256 + tid;
    int r = d16 >> 3, p = d16 & 7;
    sl16[i] = d16;
    srow[i] = r;
    scol[i] = (p ^ (r & 7)) * 8;
  }

  f32x4 acc0[4][4], acc1[4][4];
#pragma unroll
  for (int mi = 0; mi < 4; ++mi)
#pragma unroll
    for (int ni = 0; ni < 4; ++ni) {
      acc0[mi][ni] = (f32x4){0.f, 0.f, 0.f, 0.f};
      acc1[mi][ni] = (f32x4){0.f, 0.f, 0.f, 0.f};
    }

  const int rowA = bm * 128, rowB = bn * 128;
  for (int k0 = 0; k0 < DIM; k0 += 64) {
#pragma unroll
    for (int i = 0; i < 4; ++i) {
      gload_lds16(X + (size_t)(rowA + srow[i]) * DIM + k0 + scol[i], &lA[sl16[i] * 8]);
      gload_lds16(Y0 + (size_t)(rowB + srow[i]) * DIM + k0 + scol[i], &lB0[sl16[i] * 8]);
      gload_lds16(Y1 + (size_t)(rowB + srow[i]) * DIM + k0 + scol[i], &lB1[sl16[i] * 8]);
    }
    __syncthreads();
#pragma unroll
    for (int ks = 0; ks < 2; ++ks) {
      bf16x8 af[4], b0f[4], b1f[4];
#pragma unroll
      for (int mi = 0; mi < 4; ++mi) {
        int r = wm * 64 + mi * 16 + (lane & 15);
        int p = (ks * 4 + (lane >> 4)) ^ (r & 7);
        af[mi] = *(const bf16x8*)&lA[r * 64 + p * 8];
      }
#pragma unroll
      for (int ni = 0; ni < 4; ++ni) {
        int r = wn * 64 + ni * 16 + (lane & 15);
        int p = (ks * 4 + (lane >> 4)) ^ (r & 7);
        b0f[ni] = *(const bf16x8*)&lB0[r * 64 + p * 8];
        b1f[ni] = *(const bf16x8*)&lB1[r * 64 + p * 8];
      }
#pragma unroll
      for (int mi = 0; mi < 4; ++mi)
#pragma unroll
        for (int ni = 0; ni < 4; ++ni) {
          acc0[mi][ni] = __builtin_amdgcn_mfma_f32_16x16x32_bf16(af[mi], b0f[ni], acc0[mi][ni], 0, 0, 0);
          acc1[mi][ni] = __builtin_amdgcn_mfma_f32_16x16x32_bf16(af[mi], b1f[ni], acc1[mi][ni], 0, 0, 0);
        }
    }
    __syncthreads();
  }

  // ---- epilogue: tanh + bf16 mask (loaded once, reused for both b) + row/col max
  const __hip_bfloat16* mk = msk + (size_t)a * DIM * DIM;
  float rmx0[4][4], rmx1[4][4], cmx0[4], cmx1[4];
#pragma unroll
  for (int mi = 0; mi < 4; ++mi)
#pragma unroll
    for (int j = 0; j < 4; ++j) { rmx0[mi][j] = -INFINITY; rmx1[mi][j] = -INFINITY; }
#pragma unroll
  for (int ni = 0; ni < 4; ++ni) { cmx0[ni] = -INFINITY; cmx1[ni] = -INFINITY; }

#pragma unroll
  for (int mi = 0; mi < 4; ++mi) {
    int s0 = rowA + wm * 64 + mi * 16 + ((lane >> 4) << 2);
#pragma unroll
    for (int ni = 0; ni < 4; ++ni) {
      int t = rowB + wn * 64 + ni * 16 + (lane & 15);
#pragma unroll
      for (int j = 0; j < 4; ++j) {
        float m = __bfloat162float(mk[(size_t)(s0 + j) * DIM + t]);
        float v0 = tanh_fast(acc0[mi][ni][j]) + m;
        float v1 = tanh_fast(acc1[mi][ni][j]) + m;
        rmx0[mi][j] = fmaxf(rmx0[mi][j], v0);
        rmx1[mi][j] = fmaxf(rmx1[mi][j], v1);
        cmx0[ni] = fmaxf(cmx0[ni], v0);
        cmx1[ni] = fmaxf(cmx1[ni], v1);
      }
    }
  }

  const int pr0 = a * 16 + b0, pr1 = a * 16 + b1;
#pragma unroll
  for (int mi = 0; mi < 4; ++mi)
#pragma unroll
    for (int j = 0; j < 4; ++j) {
      float r0 = rmx0[mi][j], r1 = rmx1[mi][j];
      r0 = fmaxf(r0, __shfl_xor(r0, 1));
      r0 = fmaxf(r0, __shfl_xor(r0, 2));
      r0 = fmaxf(r0, __shfl_xor(r0, 4));
      r0 = fmaxf(r0, __shfl_xor(r0, 8));
      r1 = fmaxf(r1, __shfl_xor(r1, 1));
      r1 = fmaxf(r1, __shfl_xor(r1, 2));
      r1 = fmaxf(r1, __shfl_xor(r1, 4));
      r1 = fmaxf(r1, __shfl_xor(r1, 8));
      if ((lane & 15) == 0) {
        int s = rowA + wm * 64 + mi * 16 + ((lane >> 4) << 2) + j;
        atomicMax(&maxS[(size_t)pr0 * DIM + s], fenc(r0));
        atomicMax(&maxS[(size_t)pr1 * DIM + s], fenc(r1));
      }
    }
#pragma unroll
  for (int ni = 0; ni < 4; ++ni) {
    float c0 = cmx0[ni], c1 = cmx1[ni];
    c0 = fmaxf(c0, __shfl_xor(c0, 16));
    c0 = fmaxf(c0, __shfl_xor(c0, 32));
    c1 = fmaxf(c1, __shfl_xor(c1, 16));
    c1 = fmaxf(c1, __shfl_xor(c1, 32));
    if (lane < 16) {
      int t = rowB + wn * 64 + ni * 16 + lane;
      atomicMax(&maxT[(size_t)pr0 * DIM + t], fenc(c0));
      atomicMax(&maxT[(size_t)pr1 * DIM + t], fenc(c1));
    }
  }
}

// ---- pooling with FUSED softmax: out[pair][d] = sum_s mat[d][s]*softmax(max)[pair][s]
// Per-pair max/sum computed from menc by 16-thread groups; scores materialized
// per-128-slice in LDS (removes k_softmax dispatch + sc buffer).
__global__ __launch_bounds__(256) void k_pool(const float* __restrict__ A,
                                              const float* __restrict__ B,
                                              const unsigned* __restrict__ menc,
                                              float* __restrict__ out) {
  __shared__ float ta[128][65];
  __shared__ float ts[16][128];
  __shared__ float smx[16], sinv[16];
  int t = threadIdx.x;
  int d0 = blockIdx.x * 64;
  int y = blockIdx.y, side = blockIdx.z;
  const float* mat = (side ? B : A) + (size_t)y * DIM * DIM;
  const unsigned* mbase = menc + (size_t)side * 256 * DIM;
  float* ob = out + (size_t)side * 256 * DIM;
  int dl = t & 63, g = t >> 6;

  // per-pair softmax stats: 16 threads per pair (contiguous within a wave)
  {
    int p = t >> 4, j = t & 15;
    int pair = side ? (p * 16 + y) : (y * 16 + p);
    const unsigned* buf = mbase + (size_t)pair * DIM;
    float m = -INFINITY;
    for (int k = 0; k < 32; ++k) m = fmaxf(m, fdec(buf[j + 16 * k]));
    m = fmaxf(m, __shfl_xor(m, 1));
    m = fmaxf(m, __shfl_xor(m, 2));
    m = fmaxf(m, __shfl_xor(m, 4));
    m = fmaxf(m, __shfl_xor(m, 8));
    float s = 0.f;
    for (int k = 0; k < 32; ++k) s += __expf(fdec(buf[j + 16 * k]) - m);
    s += __shfl_xor(s, 1);
    s += __shfl_xor(s, 2);
    s += __shfl_xor(s, 4);
    s += __shfl_xor(s, 8);
    if (j == 0) { smx[p] = m; sinv[p] = 1.0f / s; }
  }

  float acc[4] = {0.f, 0.f, 0.f, 0.f};
  for (int st = 0; st < 4; ++st) {
    __syncthreads();
    // stage 64 d-rows x 128 s-cols, transposed into ta[s][d], float4 loads
#pragma unroll
    for (int i = 0; i < 8; ++i) {
      int idx = t + 256 * i;          // [0,2048): 64 r x 32 c4
      int r = idx >> 5, c4 = idx & 31;
      float4 v = *(const float4*)&mat[(size_t)(d0 + r) * DIM + st * 128 + c4 * 4];
      ta[c4 * 4 + 0][r] = v.x;
      ta[c4 * 4 + 1][r] = v.y;
      ta[c4 * 4 + 2][r] = v.z;
      ta[c4 * 4 + 3][r] = v.w;
    }
    // stage 16 partners x 128 normalized scores
#pragma unroll
    for (int i = 0; i < 8; ++i) {
      int idx = t + 256 * i;          // [0,2048): 16 p x 128 s
      int p = idx >> 7, s = idx & 127;
      int pair = side ? (p * 16 + y) : (y * 16 + p);
      ts[p][s] = __expf(fdec(mbase[(size_t)pair * DIM + st * 128 + s]) - smx[p]) * sinv[p];
    }
    __syncthreads();
    for (int s = 0; s < 128; ++s) {
      float v = ta[s][dl];
#pragma unroll
      for (int i = 0; i < 4; ++i) acc[i] += v * ts[g * 4 + i][s];
    }
  }
#pragma unroll
  for (int i = 0; i < 4; ++i) {
    int p = g * 4 + i;
    int pair = side ? (p * 16 + y) : (y * 16 + p);
    ob[(size_t)pair * DIM + d0 + dl] = acc[i];
  }
}

extern "C" void kernel_launch(void* const* d_in, const int* in_sizes, int n_in,
                              void* d_out, int out_size, void* d_ws, size_t ws_size,
                              hipStream_t stream) {
  (void)in_sizes; (void)n_in; (void)out_size; (void)ws_size;
  const float* A = (const float*)d_in[0];    // (16, 512, 512) d-major
  const float* B = (const float*)d_in[1];    // (16, 512, 512) d-major
  const float* msk = (const float*)d_in[2];  // (16, 512, 512)
  const float* U = (const float*)d_in[3];    // (512, 512)

  char* w = (char*)d_ws;
  __hip_bfloat16* At = (__hip_bfloat16*)(w + 0);         //  8 MB: [a][s][d]; reused as mskb after proj
  __hip_bfloat16* Bt = (__hip_bfloat16*)(w + 8388608);   //  8 MB: [b][t][e]
  __hip_bfloat16* Ut = (__hip_bfloat16*)(w + 16777216);  //  512 KB: [e][d]
  __hip_bfloat16* Pj = (__hip_bfloat16*)(w + 17301504);  //  8 MB: [a][s][e]
  unsigned* menc = (unsigned*)(w + 25690112);            //  1 MB: maxS | maxT
  __hip_bfloat16* mskb = At;                             //  aliased: At dead after proj
  unsigned* maxS = menc;
  unsigned* maxT = menc + 256 * DIM;

  k_prep<<<dim3(16, 16, 34), dim3(32, 8), 0, stream>>>(A, B, U, At, Bt, Ut, menc);
  k_proj64<<<dim3(128, 8), 256, 0, stream>>>(At, Ut, Pj);
  k_mskconv<<<4096, 256, 0, stream>>>(msk, mskb);
  k_align<<<2048, 256, 0, stream>>>(Pj, Bt, mskb, maxS, maxT);
  k_pool<<<dim3(8, 16, 2), 256, 0, stream>>>(A, B, menc, (float*)d_out);
}